// Round 20
// baseline (421.470 us; speedup 1.0000x reference)
//
#include <hip/hip_runtime.h>
#include <hip/hip_fp16.h>

#define C_ 32
#define I_ 32
#define W_ 32
#define R_ 36
#define D_ 1024
#define EPS_ 1e-8f
#define LAMBDA_ 9.0f
#define MARGIN_ 0.2f

typedef _Float16 f16;
typedef f16 half8 __attribute__((ext_vector_type(8)));
typedef f16 f16x4 __attribute__((ext_vector_type(4)));
typedef float f32x4 __attribute__((ext_vector_type(4)));

__device__ __forceinline__ void gload16(const void* g, void* l) {
    __builtin_amdgcn_global_load_lds((const __attribute__((address_space(1))) void*)g,
                                     (__attribute__((address_space(3))) void*)l, 16, 0, 0);
}

__device__ __forceinline__ f16x4 to_h4(f32x4 v) {
    f16x4 o; o[0] = (f16)v[0]; o[1] = (f16)v[1]; o[2] = (f16)v[2]; o[3] = (f16)v[3];
    return o;
}

// fp32 -> fp16 of cap, w_lin, w_gate, img. Cap segment also accumulates
// w11Buf[row] = sum_d cap^2 via per-wave reduce + atomic (4/row).
// Block 0 thread 0 builds the active-tile map.
__global__ __launch_bounds__(256) void convert_kernel(
    const float* __restrict__ cap, const float* __restrict__ wl, const float* __restrict__ wg,
    const float* __restrict__ img,
    f16* __restrict__ capH, f16* __restrict__ wlH, f16* __restrict__ wgH, f16* __restrict__ imgH,
    float* __restrict__ w11Buf,
    const int* __restrict__ lens, int* __restrict__ tileMap, int* __restrict__ activeCnt)
{
    const int t = blockIdx.x * 256 + threadIdx.x;   // 1605632 total
    if (blockIdx.x == 0 && threadIdx.x == 0) {
        int n = 0;
        for (int cm = 0; cm < 256; cm++) {
            const int len = lens[cm >> 3];
            if ((cm & 7) * 4 < len) tileMap[n++] = cm;
        }
        activeCnt[0] = n;
    }
    const float* src; f16* dst; int idx;
    bool isCap = false;
    if (t < 262144)        { src = cap; dst = capH; idx = t; isCap = true; }
    else if (t < 786432)   { src = wl;  dst = wlH;  idx = t - 262144; }
    else if (t < 1310720)  { src = wg;  dst = wgH;  idx = t - 786432; }
    else                   { src = img; dst = imgH; idx = t - 1310720; }
    float4 v = ((const float4*)src)[idx];
    f16x4 o; o[0] = (f16)v.x; o[1] = (f16)v.y; o[2] = (f16)v.z; o[3] = (f16)v.w;
    *(f16x4*)(dst + (size_t)idx * 4) = o;
    if (isCap) {
        float s = v.x * v.x + v.y * v.y + v.z * v.z + v.w * v.w;
        #pragma unroll
        for (int m = 32; m > 0; m >>= 1) s += __shfl_xor(s, m);
        if ((threadIdx.x & 63) == 0) atomicAdd(&w11Buf[t >> 8], s);
    }
}

// Merged: bid<512 -> imgW2T tile (jt=bid&15, i=bid>>4); bid>=512 -> gram (i=bid-512)
__global__ __launch_bounds__(256) void imgprep_kernel(
    const f16* __restrict__ wlinH, const f16* __restrict__ wgateH,
    const f16* __restrict__ imgH, f16* __restrict__ imgW2T, f16* __restrict__ gramH)
{
    __shared__ __align__(16) char sMem[24576];
    const int tid = threadIdx.x, lane = tid & 63, wv = tid >> 6;

    if (blockIdx.x < 512) {
        // ---- imgW2T[i][j][r] = sum_d img[i][r][d] * Wpair2[j][d] ----
        const int jt = blockIdx.x & 15;
        const int i  = blockIdx.x >> 4;
        f16* sA = (f16*)sMem;               // 128 x 64 (16 KB)
        f16* sB = (f16*)(sMem + 16384);     // 64 x 64 (8 KB)
        const int wm = wv >> 1, wn = wv & 1;
        f32x4 acc[4][2];
        #pragma unroll
        for (int a = 0; a < 4; a++) { acc[a][0] = (f32x4){0,0,0,0}; acc[a][1] = (f32x4){0,0,0,0}; }

        for (int ks = 0; ks < 16; ks++) {
            const int kk = ks * 64;
            __syncthreads();
            #pragma unroll
            for (int p = 0; p < 4; p++) {
                const int u = tid + p * 256;
                const int row = u >> 3, ch = u & 7;
                const int jr = jt * 128 + row;
                const f16* src = ((jr < 1024) ? (wlinH + (size_t)jr * 2048)
                                              : (wgateH + (size_t)(jr - 1024) * 2048))
                                 + 1024 + kk + ((ch ^ (row & 7)) << 3);
                gload16(src, (char*)sA + u * 16);
            }
            #pragma unroll
            for (int p = 0; p < 2; p++) {
                const int u = tid + p * 256;
                const int row = u >> 3, ch = u & 7;
                const f16* src = imgH + (size_t)(i * 36 + row) * 1024 + kk + ((ch ^ (row & 7)) << 3);
                gload16(src, (char*)sB + u * 16);
            }
            __syncthreads();
            #pragma unroll
            for (int ksub = 0; ksub < 2; ksub++) {
                const int kch = (ksub << 2) | (lane >> 4);
                half8 af[4], bf[2];
                #pragma unroll
                for (int tm = 0; tm < 4; tm++) {
                    const int row = wm * 64 + tm * 16 + (lane & 15);
                    af[tm] = *(const half8*)((const char*)sA + row * 128 + ((kch ^ (row & 7)) << 4));
                }
                #pragma unroll
                for (int tn = 0; tn < 2; tn++) {
                    const int row = wn * 32 + tn * 16 + (lane & 15);
                    bf[tn] = *(const half8*)((const char*)sB + row * 128 + ((kch ^ (row & 7)) << 4));
                }
                #pragma unroll
                for (int tm = 0; tm < 4; tm++)
                    #pragma unroll
                    for (int tn = 0; tn < 2; tn++)
                        acc[tm][tn] = __builtin_amdgcn_mfma_f32_16x16x32_f16(af[tm], bf[tn], acc[tm][tn], 0, 0, 0);
            }
        }
        #pragma unroll
        for (int tm = 0; tm < 4; tm++)
            #pragma unroll
            for (int tn = 0; tn < 2; tn++)
                #pragma unroll
                for (int r = 0; r < 4; r++) {
                    const int j = jt * 128 + wm * 64 + tm * 16 + (lane >> 4) * 4 + r;
                    const int rc = wn * 32 + tn * 16 + (lane & 15);
                    imgW2T[((size_t)i * 2048 + j) * 64 + rc] = (rc < 36) ? (f16)acc[tm][tn][r] : (f16)0.f;
                }
    } else {
        // ---- gramH[i][m][n] = sum_d img[i][m][d] img[i][n][d] ----
        const int i = blockIdx.x - 512;
        f16 (*sG)[6144] = (f16(*)[6144])sMem;   // 2 x 48x128

        auto stage = [&](int b, int k0) {
            for (int g = wv; g < 12; g += 4) {
                const int row = g * 4 + (lane >> 4);
                gload16(imgH + (size_t)(i * 36 + row) * 1024 + k0 + (((lane & 15) ^ (row & 7)) << 3),
                        &sG[b][g * 512]);
            }
        };

        f32x4 acc[4];
        #pragma unroll
        for (int a = 0; a < 4; a++) acc[a] = (f32x4){0.f, 0.f, 0.f, 0.f};

        stage(0, 0);
        __syncthreads();
        int cur = 0;
        for (int kc = 0; kc < 8; kc++) {
            if (kc < 7) stage(cur ^ 1, (kc + 1) * 128);
            #pragma unroll
            for (int ks = 0; ks < 4; ks++) {
                const int arow = wv * 16 + (lane & 15);
                const half8 am = *(const half8*)&sG[cur][arow * 128 + ((((ks << 2) | (lane >> 4)) ^ (arow & 7)) << 3)];
                #pragma unroll
                for (int nt = 0; nt < 4; nt++) {
                    const int brow = nt * 16 + (lane & 15);
                    const half8 bn = *(const half8*)&sG[cur][brow * 128 + ((((ks << 2) | (lane >> 4)) ^ (brow & 7)) << 3)];
                    acc[nt] = __builtin_amdgcn_mfma_f32_16x16x32_f16(am, bn, acc[nt], 0, 0, 0);
                }
            }
            __syncthreads();
            cur ^= 1;
        }
        #pragma unroll
        for (int nt = 0; nt < 4; nt++)
            #pragma unroll
            for (int r = 0; r < 4; r++) {
                const int m = wv * 16 + ((lane >> 4) << 2) + r;
                const int n = nt * 16 + (lane & 15);
                gramH[(size_t)i * 4096 + m * 64 + n] = (m < 36 && n < 36) ? (f16)acc[nt][r] : (f16)0.f;
            }
    }
}

__device__ __forceinline__ float smt_read(const f16* sSmT, int w, int r) {
    return (float)sSmT[w * 64 + ((((r >> 3) ^ (w & 7)) << 3) | (r & 7))];
}

// One WG per (c-pair, i), 4 waves, 3 blocks/CU. Single-buffer phase A.
template<int MODE>
__global__ __launch_bounds__(256, 3) void attn_kernel(
    const f16* __restrict__ imgH,
    const f16* __restrict__ gramH,      // (I,64,64)
    const f16* __restrict__ imgW2T,     // (I,2048,64)
    const f16* __restrict__ capH,
    const f16* __restrict__ qcur,       // (C,W,I,D)
    const f16* __restrict__ capW1,      // (C*W,2048)
    f16* __restrict__ capImg0,          // (C,I,W,64)
    const float* __restrict__ b_lin, const float* __restrict__ b_gate,
    const float* __restrict__ w11Buf,
    const int* __restrict__ lens,
    f16* __restrict__ preLin, f16* __restrict__ preGate,
    f16* __restrict__ qOut,
    float* __restrict__ score)
{
    constexpr int SBIG = (MODE == 2) ? 28672 : 33792;
    __shared__ __align__(16) char sBig[SBIG];
    __shared__ f16 sSmT[2][2048];
    __shared__ float sAttn[36][66];     // cols 0..31 cap0, 32..63 cap1
    __shared__ float sNrm[2][36];
    __shared__ float sW22[2][4][32];
    __shared__ float sW12f[2][32];

    const int bid = blockIdx.x;         // 0..511
    const int cp = bid >> 5;            // caption pair
    const int i  = ((bid & 7) << 2) | ((bid >> 3) & 3);   // XCD: same-i colocate
    const int c0 = cp * 2;
    const int len0 = lens[c0], len1 = lens[c0 + 1];
    const int tid = threadIdx.x;
    const int lane = tid & 63;
    const int wv = tid >> 6;
    const int i36 = i * 36;

    f16* sPA = (f16*)sBig;

    f32x4 accA[3] = {{0,0,0,0},{0,0,0,0},{0,0,0,0}};
    const int lenW = (wv >> 1) ? len1 : len0;
    const bool skipW = (MODE != 0) && ((wv & 1) == 1) && (lenW <= 16);

    auto stageA = [&](int k0) {
        for (int g = wv; g < 28; g += 4) {
            if (g < 12) {
                const int row = g * 4 + (lane >> 4);
                gload16(imgH + (size_t)(i36 + row) * 1024 + k0 + (((lane & 15) ^ (row & 7)) << 3),
                        &sPA[g * 512]);
            } else {
                const int gq = g - 12;
                const int w = gq * 4 + (lane >> 4);          // 0..63 (2 captions)
                const int lenw = (w >> 5) ? len1 : len0;
                const f16* src = (MODE == 0)
                    ? (capH + (size_t)(c0 * 32 + w) * 1024)
                    : (qcur + (((size_t)(c0 * 32 + w)) * 32 + i) * 1024);
                src += k0 + (((lane & 15) ^ (w & 7)) << 3);
                if (MODE == 0 || (w & 31) < lenw)
                    gload16(src, &sPA[6144 + gq * 512]);
            }
        }
    };

    for (int kc = 0; kc < 8; kc++) {
        stageA(kc * 128);
        __syncthreads();
        if (!skipW) {
            __builtin_amdgcn_s_setprio(1);
            #pragma unroll
            for (int ks = 0; ks < 4; ks++) {
                const int kch = (ks << 2) | (lane >> 4);
                const int brow = wv * 16 + (lane & 15);
                const half8 bf = *(const half8*)&sPA[6144 + brow * 128 + ((kch ^ (brow & 7)) << 3)];
                #pragma unroll
                for (int mt = 0; mt < 3; mt++) {
                    const int arow = mt * 16 + (lane & 15);
                    const half8 af = *(const half8*)&sPA[arow * 128 + ((kch ^ (arow & 7)) << 3)];
                    accA[mt] = __builtin_amdgcn_mfma_f32_16x16x32_f16(af, bf, accA[mt], 0, 0, 0);
                }
            }
            __builtin_amdgcn_s_setprio(0);
        }
        __syncthreads();
    }

    if (!skipW) {
        #pragma unroll
        for (int mt = 0; mt < 3; mt++) {
            #pragma unroll
            for (int r = 0; r < 4; r++) {
                const int rr = mt * 16 + (lane >> 4) * 4 + r;
                if (rr < 36) {
                    float v = accA[mt][r];
                    sAttn[rr][wv * 16 + (lane & 15)] = (v >= 0.f) ? v : 0.1f * v;
                }
            }
        }
    }
    __syncthreads();

    if (tid < 72) {
        const int cap = tid / 36;
        const int r = tid - cap * 36;
        const int lenc = cap ? len1 : len0;
        float s = 0.f;
        for (int w = 0; w < lenc; w++) { float v = sAttn[r][cap * 32 + w]; s += v * v; }
        sNrm[cap][r] = LAMBDA_ / (sqrtf(s) + EPS_);
    }
    __syncthreads();

    if (tid < 64) {
        const int cap = tid >> 5, w = tid & 31;
        const int lenc = cap ? len1 : len0;
        f16* smt = &sSmT[cap][0];
        if (w < lenc) {
            float m = -1e30f;
            #pragma unroll
            for (int r = 0; r < 36; r++) m = fmaxf(m, sAttn[r][cap * 32 + w] * sNrm[cap][r]);
            float sum = 0.f;
            #pragma unroll
            for (int r = 0; r < 36; r++) sum += __expf(sAttn[r][cap * 32 + w] * sNrm[cap][r] - m);
            const float inv = 1.0f / sum;
            #pragma unroll
            for (int r = 0; r < 64; r++) {
                const int off = w * 64 + ((((r >> 3) ^ (w & 7)) << 3) | (r & 7));
                smt[off] = (r < 36) ? (f16)(__expf(sAttn[r][cap * 32 + w] * sNrm[cap][r] - m) * inv) : (f16)0.f;
            }
        } else {
            #pragma unroll
            for (int r = 0; r < 64; r++) smt[w * 64 + r] = (f16)0.f;
        }
    }
    __syncthreads();

    if (MODE == 0) {
        const int w = tid >> 3, rg = tid & 7;
        #pragma unroll
        for (int cap = 0; cap < 2; cap++) {
            half8 o;
            #pragma unroll
            for (int k = 0; k < 8; k++) {
                const int r = rg * 8 + k;
                float v = 0.f;
                if (r < 36) { v = sAttn[r][cap * 32 + w]; v = (v >= 0.f) ? v : v * 10.f; }
                o[k] = (f16)v;
            }
            const size_t base = ((((size_t)((c0 + cap) * 32 + i)) << 5) + w) << 6;
            *(half8*)(capImg0 + base + rg * 8) = o;
        }
    }

    half8 af[2][2][2];
    #pragma unroll
    for (int cap = 0; cap < 2; cap++)
        #pragma unroll
        for (int mt = 0; mt < 2; mt++)
            #pragma unroll
            for (int ks = 0; ks < 2; ks++) {
                const int row = mt * 16 + (lane & 15);
                af[cap][mt][ks] = *(const half8*)&sSmT[cap][row * 64 + ((((ks << 2) | (lane >> 4)) ^ (row & 7)) << 3)];
            }

    // w22 = sm^T G sm (gram rows shared by both captions)
    {
        const f16* gb = gramH + ((size_t)i << 12);
        const int arow = (wv << 4) + (lane & 15);
        const half8 gA0 = *(const half8*)(gb + arow * 64 + ((lane >> 4) << 3));
        const half8 gA1 = *(const half8*)(gb + arow * 64 + 32 + ((lane >> 4) << 3));
        float w22L[2][2] = {{0.f, 0.f}, {0.f, 0.f}};
        #pragma unroll
        for (int cap = 0; cap < 2; cap++)
            #pragma unroll
            for (int mt = 0; mt < 2; mt++) {
                f32x4 t = {0.f, 0.f, 0.f, 0.f};
                t = __builtin_amdgcn_mfma_f32_16x16x32_f16(gA0, af[cap][mt][0], t, 0, 0, 0);
                t = __builtin_amdgcn_mfma_f32_16x16x32_f16(gA1, af[cap][mt][1], t, 0, 0, 0);
                const int w = mt * 16 + (lane & 15);
                const int rp = (wv << 4) + ((lane >> 4) << 2);
                #pragma unroll
                for (int r = 0; r < 4; r++)
                    w22L[cap][mt] += t[r] * smt_read(&sSmT[cap][0], w, rp + r);
            }
        #pragma unroll
        for (int cap = 0; cap < 2; cap++)
            #pragma unroll
            for (int mt = 0; mt < 2; mt++) {
                w22L[cap][mt] += __shfl_xor(w22L[cap][mt], 16);
                w22L[cap][mt] += __shfl_xor(w22L[cap][mt], 32);
            }
        if (lane < 16) {
            #pragma unroll
            for (int cap = 0; cap < 2; cap++) {
                sW22[cap][wv][lane] = w22L[cap][0];
                sW22[cap][wv][16 + lane] = w22L[cap][1];
            }
        }
    }

    // w12 = sum_r sm[w,r] * capImg[w,r]
    {
        const int w = tid >> 3, rg = tid & 7;
        #pragma unroll
        for (int cap = 0; cap < 2; cap++) {
            float p = 0.f;
            if (MODE == 0) {
                #pragma unroll
                for (int k = 0; k < 8; k++) {
                    const int r = rg * 8 + k;
                    if (r < 36) {
                        float v = sAttn[r][cap * 32 + w]; v = (v >= 0.f) ? v : v * 10.f;
                        p += v * smt_read(&sSmT[cap][0], w, r);
                    }
                }
            } else {
                const size_t base = ((((size_t)((c0 + cap) * 32 + i)) << 5) + w) << 6;
                const half8 ci8 = *(const half8*)(capImg0 + base + rg * 8);
                #pragma unroll
                for (int k = 0; k < 8; k++) {
                    const int r = rg * 8 + k;
                    if (r < 36) p += (float)ci8[k] * smt_read(&sSmT[cap][0], w, r);
                }
            }
            p += __shfl_xor(p, 1); p += __shfl_xor(p, 2); p += __shfl_xor(p, 4);
            if (rg == 0) sW12f[cap][w] = p;
        }
    }
    __syncthreads();

    if (tid < 64) {
        const int cap = tid >> 5, w = tid & 31;
        const int lenc = cap ? len1 : len0;
        float part = 0.f;
        if (w < lenc) {
            const float a = sW12f[cap][w];
            const float b = sW22[cap][0][w] + sW22[cap][1][w] + sW22[cap][2][w] + sW22[cap][3][w];
            part = a / fmaxf(sqrtf(w11Buf[(c0 + cap) * 32 + w]) * sqrtf(b), EPS_);
        }
        part += __shfl_down(part, 16);
        part += __shfl_down(part, 8);
        part += __shfl_down(part, 4);
        part += __shfl_down(part, 2);
        part += __shfl_down(part, 1);
        if ((lane & 31) == 0) score[(c0 + cap) * 32 + i] += part / (float)lenc;
    }

    // ---- pre / qOut: imgW2T fragments shared by both captions; next-t prefetch ----
    if (MODE == 1) {
        f16 (*tiles)[4][32][66] = (f16(*)[4][32][66])sBig;   // [dbuf][cap*2+sub][w][j]
        const f16* w2base = imgW2T + (((size_t)i * 2048) << 6);
        half8 nb[2][2];
        {
            #pragma unroll
            for (int s = 0; s < 2; s++) {
                const int jA = (s * 4 + wv) * 16 + (lane & 15);    // subs 0,1
                const f16* bb = w2base + ((size_t)jA << 6);
                nb[s][0] = *(const half8*)(bb + ((lane >> 4) << 3));
                nb[s][1] = *(const half8*)(bb + 32 + ((lane >> 4) << 3));
            }
        }
        for (int t = 0; t < 16; t++) {
            half8 bf[2][2];
            #pragma unroll
            for (int s = 0; s < 2; s++) { bf[s][0] = nb[s][0]; bf[s][1] = nb[s][1]; }
            if (t < 15) {
                #pragma unroll
                for (int s = 0; s < 2; s++) {
                    const int sub = (t + 1) * 2 + s;
                    const int jA = (sub * 4 + wv) * 16 + (lane & 15);
                    const f16* bb = w2base + ((size_t)jA << 6);
                    nb[s][0] = *(const half8*)(bb + ((lane >> 4) << 3));
                    nb[s][1] = *(const half8*)(bb + 32 + ((lane >> 4) << 3));
                }
            }
            __builtin_amdgcn_s_setprio(1);
            #pragma unroll
            for (int s = 0; s < 2; s++)
                #pragma unroll
                for (int cap = 0; cap < 2; cap++)
                    #pragma unroll
                    for (int mt = 0; mt < 2; mt++) {
                        f32x4 acc = {0.f, 0.f, 0.f, 0.f};
                        acc = __builtin_amdgcn_mfma_f32_16x16x32_f16(bf[s][0], af[cap][mt][0], acc, 0, 0, 0);
                        acc = __builtin_amdgcn_mfma_f32_16x16x32_f16(bf[s][1], af[cap][mt][1], acc, 0, 0, 0);
                        const int w = mt * 16 + (lane & 15);
                        *(f16x4*)&tiles[t & 1][cap * 2 + s][w][wv * 16 + ((lane >> 4) << 2)] = to_h4(acc);
                    }
            __builtin_amdgcn_s_setprio(0);
            __syncthreads();
            const int w = tid >> 3, jg = tid & 7;
            #pragma unroll
            for (int s = 0; s < 2; s++) {
                const int sub = t * 2 + s;
                f16* dst = (sub < 16) ? preLin : preGate;
                const int joff = ((sub * 64) & 1023) + jg * 8;
                #pragma unroll
                for (int cap = 0; cap < 2; cap++) {
                    const int lenc = cap ? len1 : len0;
                    if (w < lenc) {
                        const half8 v = *(const half8*)&tiles[t & 1][cap * 2 + s][w][jg * 8];
                        *(half8*)(dst + (((size_t)((c0 + cap) * 32 + w) * 32 + i) << 10) + joff) = v;
                    }
                }
            }
        }
    } else if (MODE == 0) {
        f16 (*tiles)[4][32][66] = (f16(*)[4][32][66])sBig;  // [dbuf][cap*2+LG][w][j]
        const f16* w2base = imgW2T + (((size_t)i * 2048) << 6);
        half8 nL0, nL1, nG0, nG1;
        {
            const int jA = wv * 16 + (lane & 15);            // t = 0
            const f16* bbL = w2base + ((size_t)jA << 6);
            const f16* bbG = w2base + ((size_t)(1024 + jA) << 6);
            nL0 = *(const half8*)(bbL + ((lane >> 4) << 3));
            nL1 = *(const half8*)(bbL + 32 + ((lane >> 4) << 3));
            nG0 = *(const half8*)(bbG + ((lane >> 4) << 3));
            nG1 = *(const half8*)(bbG + 32 + ((lane >> 4) << 3));
        }
        for (int t = 0; t < 16; t++) {
            const half8 bL0 = nL0, bL1 = nL1, bG0 = nG0, bG1 = nG1;
            if (t < 15) {
                const int jA = ((t + 1) * 4 + wv) * 16 + (lane & 15);
                const f16* bbL = w2base + ((size_t)jA << 6);
                const f16* bbG = w2base + ((size_t)(1024 + jA) << 6);
                nL0 = *(const half8*)(bbL + ((lane >> 4) << 3));
                nL1 = *(const half8*)(bbL + 32 + ((lane >> 4) << 3));
                nG0 = *(const half8*)(bbG + ((lane >> 4) << 3));
                nG1 = *(const half8*)(bbG + 32 + ((lane >> 4) << 3));
            }
            __builtin_amdgcn_s_setprio(1);
            #pragma unroll
            for (int cap = 0; cap < 2; cap++)
                #pragma unroll
                for (int mt = 0; mt < 2; mt++) {
                    f32x4 aL = {0.f, 0.f, 0.f, 0.f}, aG = {0.f, 0.f, 0.f, 0.f};
                    aL = __builtin_amdgcn_mfma_f32_16x16x32_f16(bL0, af[cap][mt][0], aL, 0, 0, 0);
                    aL = __builtin_amdgcn_mfma_f32_16x16x32_f16(bL1, af[cap][mt][1], aL, 0, 0, 0);
                    aG = __builtin_amdgcn_mfma_f32_16x16x32_f16(bG0, af[cap][mt][0], aG, 0, 0, 0);
                    aG = __builtin_amdgcn_mfma_f32_16x16x32_f16(bG1, af[cap][mt][1], aG, 0, 0, 0);
                    const int w = mt * 16 + (lane & 15);
                    const int x = wv * 16 + ((lane >> 4) << 2);
                    *(f16x4*)&tiles[t & 1][cap * 2 + 0][w][x] = to_h4(aL);
                    *(f16x4*)&tiles[t & 1][cap * 2 + 1][w][x] = to_h4(aG);
                }
            __builtin_amdgcn_s_setprio(0);
            __syncthreads();
            const int w = tid >> 3, jg = tid & 7;
            const int j = t * 64 + jg * 8;
            #pragma unroll
            for (int cap = 0; cap < 2; cap++) {
                const int lenc = cap ? len1 : len0;
                if (w < lenc) {
                    const size_t cw = (size_t)((c0 + cap) * 32 + w);
                    const half8 l8 = *(const half8*)&tiles[t & 1][cap * 2 + 0][w][jg * 8];
                    const half8 g8 = *(const half8*)&tiles[t & 1][cap * 2 + 1][w][jg * 8];
                    const half8 c1L = *(const half8*)(capW1 + cw * 2048 + j);
                    const half8 c1G = *(const half8*)(capW1 + cw * 2048 + 1024 + j);
                    const half8 cp8 = *(const half8*)(capH + cw * 1024 + j);
                    half8 o;
                    #pragma unroll
                    for (int k = 0; k < 8; k++) {
                        const float h = tanhf((float)l8[k] + (float)c1L[k] + b_lin[j + k]);
                        const float g = 1.f / (1.f + __expf(-((float)g8[k] + (float)c1G[k] + b_gate[j + k])));
                        o[k] = (f16)((float)cp8[k] * g + h * (1.f - g));
                    }
                    *(half8*)(qOut + ((cw * 32 + i) << 10) + j) = o;
                }
            }
        }
    }
}

// q-half GEMM: m97 geometry. BM=128, BN=128 (64 j x {lin,gate}), BK=64,
// 256 thr / 4 waves (2m x 2n), acc[4][4], single-buffer LDS, 2-barrier K-step.
// (256,4): min 4 waves/EU — VGPR cap 128 == current natural allocation.
__global__ __launch_bounds__(256, 4) void qgemm_kernel(
    const f16* __restrict__ Aptr,
    const f16* __restrict__ wlinH, const f16* __restrict__ wgateH,
    const f16* __restrict__ preLin, const f16* __restrict__ preGate,
    const float* __restrict__ b_lin, const float* __restrict__ b_gate,
    f16* __restrict__ outp,
    const int* __restrict__ lens,
    const int* __restrict__ tileMap, const int* __restrict__ activeCnt,
    const int mode)
{
    const int bid = blockIdx.x;
    int jt, cm;
    if (mode) {
        const int x = bid & 7;
        jt = (bid >> 3) & 15;
        const int s = bid >> 7;
        const int a = s * 8 + x;
        if (a >= activeCnt[0]) return;
        cm = tileMap[a];
    } else {
        jt = bid & 15; cm = bid >> 4;
    }
    int len = 32;
    if (mode) len = lens[cm >> 3];
    const int m0 = cm * 128;

    __shared__ f16 sA[128 * 64];
    __shared__ f16 sB[128 * 64];

    const int tid = threadIdx.x;
    const int lane = tid & 63;
    const int wv = tid >> 6;
    const int wm = wv >> 1;
    const int wn = wv & 1;

    f32x4 acc[4][4];
    #pragma unroll
    for (int a = 0; a < 4; a++)
        #pragma unroll
        for (int b = 0; b < 4; b++)
            acc[a][b] = (f32x4){0.f, 0.f, 0.f, 0.f};

    for (int ks = 0; ks < 16; ks++) {
        const int kk = ks * 64;
        #pragma unroll
        for (int p = 0; p < 4; p++) {
            const int idx = tid + p * 256;
            const int row = idx >> 3, ch = idx & 7;
            gload16(Aptr + (size_t)(m0 + row) * 1024 + kk + ((ch ^ (row & 7)) << 3),
                    (char*)sA + idx * 16);
        }
        #pragma unroll
        for (int p = 0; p < 4; p++) {
            const int idx = tid + p * 256;
            const int n = idx >> 3, ch = idx & 7;
            const int j = jt * 64 + (n & 63);
            const f16* wsrc = ((n < 64) ? wlinH : wgateH) + (size_t)j * 2048 + kk + ((ch ^ (n & 7)) << 3);
            gload16(wsrc, (char*)sB + idx * 16);
        }
        __syncthreads();
        #pragma unroll
        for (int ksub = 0; ksub < 2; ksub++) {
            const int k4 = (ksub << 2) | (lane >> 4);
            half8 afr[4], bfr[4];
            #pragma unroll
            for (int tm = 0; tm < 4; tm++) {
                const int row = wm * 64 + tm * 16 + (lane & 15);
                afr[tm] = *(const half8*)((const char*)sA + row * 128 + ((k4 ^ (row & 7)) << 4));
            }
            #pragma unroll
            for (int tn = 0; tn < 4; tn++) {
                const int n = wn * 64 + tn * 16 + (lane & 15);
                bfr[tn] = *(const half8*)((const char*)sB + n * 128 + ((k4 ^ (n & 7)) << 4));
            }
            #pragma unroll
            for (int tm = 0; tm < 4; tm++)
                #pragma unroll
                for (int tn = 0; tn < 4; tn++)
                    acc[tm][tn] = __builtin_amdgcn_mfma_f32_16x16x32_f16(afr[tm], bfr[tn], acc[tm][tn], 0, 0, 0);
        }
        __syncthreads();
    }

    // ---- LDS-staged epilogue: 2 passes of 64 rows, reuse sA/sB as C tiles
    f16 (*tl)[68] = (f16(*)[68])sA;
    f16 (*tg)[68] = (f16(*)[68])sB;
    const int j0 = (tid & 3) * 16;
    const int j = jt * 64 + j0;
    f32x4 blv[4], bgv[4];
    if (mode == 1) {
        #pragma unroll
        for (int q = 0; q < 4; q++) {
            blv[q] = *(const f32x4*)(b_lin + j + q * 4);
            bgv[q] = *(const f32x4*)(b_gate + j + q * 4);
        }
    }
    #pragma unroll
    for (int p = 0; p < 2; p++) {
        __syncthreads();
        if (wm == p) {
            #pragma unroll
            for (int tm = 0; tm < 4; tm++)
                #pragma unroll
                for (int tn = 0; tn < 4; tn++) {
                    const int n = wn * 64 + tn * 16 + (lane & 15);
                    #pragma unroll
                    for (int r = 0; r < 4; r++) {
                        const int ml = tm * 16 + ((lane >> 4) << 2) + r;
                        if (n < 64) tl[ml][n] = (f16)acc[tm][tn][r];
                        else        tg[ml][n - 64] = (f16)acc[tm][tn][r];
                    }
                }
        }
        __syncthreads();
        const int rl = tid >> 2;
        const int gm = m0 + p * 64 + rl;
        bool active = true;
        if (mode) active = (((gm >> 5) & 31) < len);
        if (active) {
            const half8 l0 = *(const half8*)&tl[rl][j0];
            const half8 l1 = *(const half8*)&tl[rl][j0 + 8];
            const half8 g0 = *(const half8*)&tg[rl][j0];
            const half8 g1 = *(const half8*)&tg[rl][j0 + 8];
            if (mode == 0) {
                *(half8*)(outp + (size_t)gm * 2048 + j) = l0;
                *(half8*)(outp + (size_t)gm * 2048 + j + 8) = l1;
                *(half8*)(outp + (size_t)gm * 2048 + 1024 + j) = g0;
                *(half8*)(outp + (size_t)gm * 2048 + 1024 + j + 8) = g1;
            } else {
                const size_t off = ((size_t)gm << 10) + j;
                const half8 pl0 = *(const half8*)(preLin + off);
                const half8 pl1 = *(const half8*)(preLin + off + 8);
                const half8 pg0 = *(const half8*)(preGate + off);
                const half8 pg1 = *(const half8*)(preGate + off + 8);
                const half8 qo0 = *(const half8*)(Aptr + off);
                const half8 qo1 = *(const half8*)(Aptr + off + 8);
                half8 o0, o1;
                #pragma unroll
                for (int k = 0; k < 8; k++) {
                    const float h = tanhf((float)l0[k] + (float)pl0[k] + blv[k >> 2][k & 3]);
                    const float g = 1.f / (1.f + __expf(-((float)g0[k] + (float)pg0[k] + bgv[k >> 2][k & 3])));
                    o0[k] = (f16)((float)qo0[k] * g + h * (1.f - g));
                }
                #pragma unroll
                for (int k = 0; k < 8; k++) {
                    const float h = tanhf((float)l1[k] + (float)pl1[k] + blv[2 + (k >> 2)][k & 3]);
                    const float g = 1.f / (1.f + __expf(-((float)g1[k] + (float)pg1[k] + bgv[2 + (k >> 2)][k & 3])));
                    o1[k] = (f16)((float)qo1[k] * g + h * (1.f - g));
                }
                *(half8*)(outp + off) = o0;
                *(half8*)(outp + off + 8) = o1;
            }
        }
    }
}

__global__ __launch_bounds__(64) void loss_kernel(const float* __restrict__ score,
                                                  float* __restrict__ out)
{
    __shared__ float s[32][33];
    __shared__ float diag[32];
    const int tid = threadIdx.x;
    for (int idx = tid; idx < 1024; idx += 64) s[idx >> 5][idx & 31] = score[idx];
    __syncthreads();
    if (tid < 32) diag[tid] = s[tid][tid];
    __syncthreads();
    float total = 0.f;
    if (tid < 32) {
        float m1 = 0.f, m2 = 0.f;
        for (int k = 0; k < 32; k++) {
            if (k != tid) {
                m1 = fmaxf(m1, fmaxf(0.f, MARGIN_ + s[tid][k] - diag[tid]));
                m2 = fmaxf(m2, fmaxf(0.f, MARGIN_ + s[k][tid] - diag[tid]));
            }
        }
        total = m1 + m2;
    }
    for (int off = 32; off > 0; off >>= 1) total += __shfl_down(total, off);
    if (tid == 0) out[0] = total;
}

extern "C" void kernel_launch(void* const* d_in, const int* in_sizes, int n_in,
                              void* d_out, int out_size, void* d_ws, size_t ws_size,
                              hipStream_t stream) {
    const float* img    = (const float*)d_in[0];
    const float* cap    = (const float*)d_in[1];
    const int*   lens   = (const int*)d_in[2];
    const float* w_lin  = (const float*)d_in[3];
    const float* b_lin  = (const float*)d_in[4];
    const float* w_gate = (const float*)d_in[5];
    const float* b_gate = (const float*)d_in[6];
    float* out = (float*)d_out;

    char* ws = (char*)d_ws;
    f16* qA      = (f16*)(ws);                       // 64 MB
    f16* preLin  = (f16*)(ws + 67108864);            // 64 MB (qB aliases)
    f16* preGate = (f16*)(ws + 134217728);           // 64 MB
    f16* capH    = (f16*)(ws + 201326592);           // 2 MB
    f16* wlinH   = (f16*)(ws + 203423744);           // 4 MB
    f16* wgateH  = (f16*)(ws + 207618048);           // 4 MB
    f16* imgH    = (f16*)(ws + 211812352);           // ~2.4 MB used
    f16* gramH   = (f16*)(ws + 214958080);           // 256 KB
    f16* capImg0 = (f16*)(ws + 216006656);           // 4 MB
    f16* imgW2T  = (f16*)(ws + 220200960);           // 8 MB
    f16* capW1   = (f16*)(ws + 228589568);           // 4 MB
    float* w11Buf = (float*)(ws + 232783872);        // 4 KB
    float* score  = (float*)(ws + 232787968);        // 4 KB
    int* tileMap  = (int*)(ws + 232792064);          // 1 KB
    int* activeCnt= (int*)(ws + 232793088);
    f16* qB = preLin;                                // alias

    hipMemsetAsync(score, 0, C_ * I_ * sizeof(float), stream);
    hipMemsetAsync(w11Buf, 0, C_ * W_ * sizeof(float), stream);
    convert_kernel<<<dim3(6272), dim3(256), 0, stream>>>(cap, w_lin, w_gate, img,
                                                         capH, wlinH, wgateH, imgH,
                                                         w11Buf, lens, tileMap, activeCnt);
    imgprep_kernel<<<dim3(544), dim3(256), 0, stream>>>(wlinH, wgateH, imgH, imgW2T, gramH);
    qgemm_kernel<<<dim3(128), dim3(256), 0, stream>>>(capH, wlinH, wgateH, (const f16*)0, (const f16*)0,
                                                      b_lin, b_gate, capW1, lens, tileMap, activeCnt, 0);
    // iter 0
    attn_kernel<0><<<dim3(512), dim3(256), 0, stream>>>(imgH, gramH, imgW2T, capH, (const f16*)0,
                                                        capW1, capImg0, b_lin, b_gate, w11Buf, lens,
                                                        preLin, preGate, qA, score);
    // iter 1
    attn_kernel<1><<<dim3(512), dim3(256), 0, stream>>>(imgH, gramH, imgW2T, capH, qA,
                                                        capW1, capImg0, b_lin, b_gate, w11Buf, lens,
                                                        preLin, preGate, (f16*)0, score);
    qgemm_kernel<<<dim3(2432), dim3(256), 0, stream>>>(qA, wlinH, wgateH, preLin, preGate,
                                                       b_lin, b_gate, qB, lens, tileMap, activeCnt, 1);
    // iter 2
    attn_kernel<2><<<dim3(512), dim3(256), 0, stream>>>(imgH, gramH, imgW2T, capH, qB,
                                                        capW1, capImg0, b_lin, b_gate, w11Buf, lens,
                                                        preLin, preGate, (f16*)0, score);

    loss_kernel<<<dim3(1), dim3(64), 0, stream>>>(score, out);
}

// Round 21
// 394.283 us; speedup vs baseline: 1.0690x; 1.0690x over previous
//
#include <hip/hip_runtime.h>
#include <hip/hip_fp16.h>

#define C_ 32
#define I_ 32
#define W_ 32
#define R_ 36
#define D_ 1024
#define EPS_ 1e-8f
#define LAMBDA_ 9.0f
#define MARGIN_ 0.2f

typedef _Float16 f16;
typedef f16 half8 __attribute__((ext_vector_type(8)));
typedef f16 f16x4 __attribute__((ext_vector_type(4)));
typedef float f32x4 __attribute__((ext_vector_type(4)));

__device__ __forceinline__ void gload16(const void* g, void* l) {
    __builtin_amdgcn_global_load_lds((const __attribute__((address_space(1))) void*)g,
                                     (__attribute__((address_space(3))) void*)l, 16, 0, 0);
}

__device__ __forceinline__ f16x4 to_h4(f32x4 v) {
    f16x4 o; o[0] = (f16)v[0]; o[1] = (f16)v[1]; o[2] = (f16)v[2]; o[3] = (f16)v[3];
    return o;
}

// fp32 -> fp16 of cap, w_lin, w_gate, img. Cap segment also accumulates
// w11Buf[row] = sum_d cap^2 via per-wave reduce + atomic (4/row).
// Block 0 thread 0 builds the active-tile map.
__global__ __launch_bounds__(256) void convert_kernel(
    const float* __restrict__ cap, const float* __restrict__ wl, const float* __restrict__ wg,
    const float* __restrict__ img,
    f16* __restrict__ capH, f16* __restrict__ wlH, f16* __restrict__ wgH, f16* __restrict__ imgH,
    float* __restrict__ w11Buf,
    const int* __restrict__ lens, int* __restrict__ tileMap, int* __restrict__ activeCnt)
{
    const int t = blockIdx.x * 256 + threadIdx.x;   // 1605632 total
    if (blockIdx.x == 0 && threadIdx.x == 0) {
        int n = 0;
        for (int cm = 0; cm < 256; cm++) {
            const int len = lens[cm >> 3];
            if ((cm & 7) * 4 < len) tileMap[n++] = cm;
        }
        activeCnt[0] = n;
    }
    const float* src; f16* dst; int idx;
    bool isCap = false;
    if (t < 262144)        { src = cap; dst = capH; idx = t; isCap = true; }
    else if (t < 786432)   { src = wl;  dst = wlH;  idx = t - 262144; }
    else if (t < 1310720)  { src = wg;  dst = wgH;  idx = t - 786432; }
    else                   { src = img; dst = imgH; idx = t - 1310720; }
    float4 v = ((const float4*)src)[idx];
    f16x4 o; o[0] = (f16)v.x; o[1] = (f16)v.y; o[2] = (f16)v.z; o[3] = (f16)v.w;
    *(f16x4*)(dst + (size_t)idx * 4) = o;
    if (isCap) {
        float s = v.x * v.x + v.y * v.y + v.z * v.z + v.w * v.w;
        #pragma unroll
        for (int m = 32; m > 0; m >>= 1) s += __shfl_xor(s, m);
        if ((threadIdx.x & 63) == 0) atomicAdd(&w11Buf[t >> 8], s);
    }
}

// Merged: bid<512 -> imgW2T tile (jt=bid&15, i=bid>>4); bid>=512 -> gram (i=bid-512)
__global__ __launch_bounds__(256) void imgprep_kernel(
    const f16* __restrict__ wlinH, const f16* __restrict__ wgateH,
    const f16* __restrict__ imgH, f16* __restrict__ imgW2T, f16* __restrict__ gramH)
{
    __shared__ __align__(16) char sMem[24576];
    const int tid = threadIdx.x, lane = tid & 63, wv = tid >> 6;

    if (blockIdx.x < 512) {
        // ---- imgW2T[i][j][r] = sum_d img[i][r][d] * Wpair2[j][d] ----
        const int jt = blockIdx.x & 15;
        const int i  = blockIdx.x >> 4;
        f16* sA = (f16*)sMem;               // 128 x 64 (16 KB)
        f16* sB = (f16*)(sMem + 16384);     // 64 x 64 (8 KB)
        const int wm = wv >> 1, wn = wv & 1;
        f32x4 acc[4][2];
        #pragma unroll
        for (int a = 0; a < 4; a++) { acc[a][0] = (f32x4){0,0,0,0}; acc[a][1] = (f32x4){0,0,0,0}; }

        for (int ks = 0; ks < 16; ks++) {
            const int kk = ks * 64;
            __syncthreads();
            #pragma unroll
            for (int p = 0; p < 4; p++) {
                const int u = tid + p * 256;
                const int row = u >> 3, ch = u & 7;
                const int jr = jt * 128 + row;
                const f16* src = ((jr < 1024) ? (wlinH + (size_t)jr * 2048)
                                              : (wgateH + (size_t)(jr - 1024) * 2048))
                                 + 1024 + kk + ((ch ^ (row & 7)) << 3);
                gload16(src, (char*)sA + u * 16);
            }
            #pragma unroll
            for (int p = 0; p < 2; p++) {
                const int u = tid + p * 256;
                const int row = u >> 3, ch = u & 7;
                const f16* src = imgH + (size_t)(i * 36 + row) * 1024 + kk + ((ch ^ (row & 7)) << 3);
                gload16(src, (char*)sB + u * 16);
            }
            __syncthreads();
            #pragma unroll
            for (int ksub = 0; ksub < 2; ksub++) {
                const int kch = (ksub << 2) | (lane >> 4);
                half8 af[4], bf[2];
                #pragma unroll
                for (int tm = 0; tm < 4; tm++) {
                    const int row = wm * 64 + tm * 16 + (lane & 15);
                    af[tm] = *(const half8*)((const char*)sA + row * 128 + ((kch ^ (row & 7)) << 4));
                }
                #pragma unroll
                for (int tn = 0; tn < 2; tn++) {
                    const int row = wn * 32 + tn * 16 + (lane & 15);
                    bf[tn] = *(const half8*)((const char*)sB + row * 128 + ((kch ^ (row & 7)) << 4));
                }
                #pragma unroll
                for (int tm = 0; tm < 4; tm++)
                    #pragma unroll
                    for (int tn = 0; tn < 2; tn++)
                        acc[tm][tn] = __builtin_amdgcn_mfma_f32_16x16x32_f16(af[tm], bf[tn], acc[tm][tn], 0, 0, 0);
            }
        }
        #pragma unroll
        for (int tm = 0; tm < 4; tm++)
            #pragma unroll
            for (int tn = 0; tn < 2; tn++)
                #pragma unroll
                for (int r = 0; r < 4; r++) {
                    const int j = jt * 128 + wm * 64 + tm * 16 + (lane >> 4) * 4 + r;
                    const int rc = wn * 32 + tn * 16 + (lane & 15);
                    imgW2T[((size_t)i * 2048 + j) * 64 + rc] = (rc < 36) ? (f16)acc[tm][tn][r] : (f16)0.f;
                }
    } else {
        // ---- gramH[i][m][n] = sum_d img[i][m][d] img[i][n][d] ----
        const int i = blockIdx.x - 512;
        f16 (*sG)[6144] = (f16(*)[6144])sMem;   // 2 x 48x128

        auto stage = [&](int b, int k0) {
            for (int g = wv; g < 12; g += 4) {
                const int row = g * 4 + (lane >> 4);
                gload16(imgH + (size_t)(i * 36 + row) * 1024 + k0 + (((lane & 15) ^ (row & 7)) << 3),
                        &sG[b][g * 512]);
            }
        };

        f32x4 acc[4];
        #pragma unroll
        for (int a = 0; a < 4; a++) acc[a] = (f32x4){0.f, 0.f, 0.f, 0.f};

        stage(0, 0);
        __syncthreads();
        int cur = 0;
        for (int kc = 0; kc < 8; kc++) {
            if (kc < 7) stage(cur ^ 1, (kc + 1) * 128);
            #pragma unroll
            for (int ks = 0; ks < 4; ks++) {
                const int arow = wv * 16 + (lane & 15);
                const half8 am = *(const half8*)&sG[cur][arow * 128 + ((((ks << 2) | (lane >> 4)) ^ (arow & 7)) << 3)];
                #pragma unroll
                for (int nt = 0; nt < 4; nt++) {
                    const int brow = nt * 16 + (lane & 15);
                    const half8 bn = *(const half8*)&sG[cur][brow * 128 + ((((ks << 2) | (lane >> 4)) ^ (brow & 7)) << 3)];
                    acc[nt] = __builtin_amdgcn_mfma_f32_16x16x32_f16(am, bn, acc[nt], 0, 0, 0);
                }
            }
            __syncthreads();
            cur ^= 1;
        }
        #pragma unroll
        for (int nt = 0; nt < 4; nt++)
            #pragma unroll
            for (int r = 0; r < 4; r++) {
                const int m = wv * 16 + ((lane >> 4) << 2) + r;
                const int n = nt * 16 + (lane & 15);
                gramH[(size_t)i * 4096 + m * 64 + n] = (m < 36 && n < 36) ? (f16)acc[nt][r] : (f16)0.f;
            }
    }
}

__device__ __forceinline__ float smt_read(const f16* sSmT, int w, int r) {
    return (float)sSmT[w * 64 + ((((r >> 3) ^ (w & 7)) << 3) | (r & 7))];
}

// One WG per (c-pair, i), 4 waves, 3 blocks/CU. Single-buffer phase A.
template<int MODE>
__global__ __launch_bounds__(256, 3) void attn_kernel(
    const f16* __restrict__ imgH,
    const f16* __restrict__ gramH,      // (I,64,64)
    const f16* __restrict__ imgW2T,     // (I,2048,64)
    const f16* __restrict__ capH,
    const f16* __restrict__ qcur,       // (C,W,I,D)
    const f16* __restrict__ capW1,      // (C*W,2048)
    f16* __restrict__ capImg0,          // (C,I,W,64)
    const float* __restrict__ b_lin, const float* __restrict__ b_gate,
    const float* __restrict__ w11Buf,
    const int* __restrict__ lens,
    f16* __restrict__ preLin, f16* __restrict__ preGate,
    f16* __restrict__ qOut,
    float* __restrict__ score)
{
    constexpr int SBIG = (MODE == 2) ? 28672 : 33792;
    __shared__ __align__(16) char sBig[SBIG];
    __shared__ f16 sSmT[2][2048];
    __shared__ float sAttn[36][66];     // cols 0..31 cap0, 32..63 cap1
    __shared__ float sNrm[2][36];
    __shared__ float sW22[2][4][32];
    __shared__ float sW12f[2][32];

    const int bid = blockIdx.x;         // 0..511
    const int cp = bid >> 5;            // caption pair
    const int i  = ((bid & 7) << 2) | ((bid >> 3) & 3);   // XCD: same-i colocate
    const int c0 = cp * 2;
    const int len0 = lens[c0], len1 = lens[c0 + 1];
    const int tid = threadIdx.x;
    const int lane = tid & 63;
    const int wv = tid >> 6;
    const int i36 = i * 36;

    f16* sPA = (f16*)sBig;

    f32x4 accA[3] = {{0,0,0,0},{0,0,0,0},{0,0,0,0}};
    const int lenW = (wv >> 1) ? len1 : len0;
    const bool skipW = (MODE != 0) && ((wv & 1) == 1) && (lenW <= 16);

    auto stageA = [&](int k0) {
        for (int g = wv; g < 28; g += 4) {
            if (g < 12) {
                const int row = g * 4 + (lane >> 4);
                gload16(imgH + (size_t)(i36 + row) * 1024 + k0 + (((lane & 15) ^ (row & 7)) << 3),
                        &sPA[g * 512]);
            } else {
                const int gq = g - 12;
                const int w = gq * 4 + (lane >> 4);          // 0..63 (2 captions)
                const int lenw = (w >> 5) ? len1 : len0;
                const f16* src = (MODE == 0)
                    ? (capH + (size_t)(c0 * 32 + w) * 1024)
                    : (qcur + (((size_t)(c0 * 32 + w)) * 32 + i) * 1024);
                src += k0 + (((lane & 15) ^ (w & 7)) << 3);
                if (MODE == 0 || (w & 31) < lenw)
                    gload16(src, &sPA[6144 + gq * 512]);
            }
        }
    };

    for (int kc = 0; kc < 8; kc++) {
        stageA(kc * 128);
        __syncthreads();
        if (!skipW) {
            __builtin_amdgcn_s_setprio(1);
            #pragma unroll
            for (int ks = 0; ks < 4; ks++) {
                const int kch = (ks << 2) | (lane >> 4);
                const int brow = wv * 16 + (lane & 15);
                const half8 bf = *(const half8*)&sPA[6144 + brow * 128 + ((kch ^ (brow & 7)) << 3)];
                #pragma unroll
                for (int mt = 0; mt < 3; mt++) {
                    const int arow = mt * 16 + (lane & 15);
                    const half8 af = *(const half8*)&sPA[arow * 128 + ((kch ^ (arow & 7)) << 3)];
                    accA[mt] = __builtin_amdgcn_mfma_f32_16x16x32_f16(af, bf, accA[mt], 0, 0, 0);
                }
            }
            __builtin_amdgcn_s_setprio(0);
        }
        __syncthreads();
    }

    if (!skipW) {
        #pragma unroll
        for (int mt = 0; mt < 3; mt++) {
            #pragma unroll
            for (int r = 0; r < 4; r++) {
                const int rr = mt * 16 + (lane >> 4) * 4 + r;
                if (rr < 36) {
                    float v = accA[mt][r];
                    sAttn[rr][wv * 16 + (lane & 15)] = (v >= 0.f) ? v : 0.1f * v;
                }
            }
        }
    }
    __syncthreads();

    if (tid < 72) {
        const int cap = tid / 36;
        const int r = tid - cap * 36;
        const int lenc = cap ? len1 : len0;
        float s = 0.f;
        for (int w = 0; w < lenc; w++) { float v = sAttn[r][cap * 32 + w]; s += v * v; }
        sNrm[cap][r] = LAMBDA_ / (sqrtf(s) + EPS_);
    }
    __syncthreads();

    if (tid < 64) {
        const int cap = tid >> 5, w = tid & 31;
        const int lenc = cap ? len1 : len0;
        f16* smt = &sSmT[cap][0];
        if (w < lenc) {
            float m = -1e30f;
            #pragma unroll
            for (int r = 0; r < 36; r++) m = fmaxf(m, sAttn[r][cap * 32 + w] * sNrm[cap][r]);
            float sum = 0.f;
            #pragma unroll
            for (int r = 0; r < 36; r++) sum += __expf(sAttn[r][cap * 32 + w] * sNrm[cap][r] - m);
            const float inv = 1.0f / sum;
            #pragma unroll
            for (int r = 0; r < 64; r++) {
                const int off = w * 64 + ((((r >> 3) ^ (w & 7)) << 3) | (r & 7));
                smt[off] = (r < 36) ? (f16)(__expf(sAttn[r][cap * 32 + w] * sNrm[cap][r] - m) * inv) : (f16)0.f;
            }
        } else {
            #pragma unroll
            for (int r = 0; r < 64; r++) smt[w * 64 + r] = (f16)0.f;
        }
    }
    __syncthreads();

    if (MODE == 0) {
        const int w = tid >> 3, rg = tid & 7;
        #pragma unroll
        for (int cap = 0; cap < 2; cap++) {
            half8 o;
            #pragma unroll
            for (int k = 0; k < 8; k++) {
                const int r = rg * 8 + k;
                float v = 0.f;
                if (r < 36) { v = sAttn[r][cap * 32 + w]; v = (v >= 0.f) ? v : v * 10.f; }
                o[k] = (f16)v;
            }
            const size_t base = ((((size_t)((c0 + cap) * 32 + i)) << 5) + w) << 6;
            *(half8*)(capImg0 + base + rg * 8) = o;
        }
    }

    half8 af[2][2][2];
    #pragma unroll
    for (int cap = 0; cap < 2; cap++)
        #pragma unroll
        for (int mt = 0; mt < 2; mt++)
            #pragma unroll
            for (int ks = 0; ks < 2; ks++) {
                const int row = mt * 16 + (lane & 15);
                af[cap][mt][ks] = *(const half8*)&sSmT[cap][row * 64 + ((((ks << 2) | (lane >> 4)) ^ (row & 7)) << 3)];
            }

    // w22 = sm^T G sm (gram rows shared by both captions)
    {
        const f16* gb = gramH + ((size_t)i << 12);
        const int arow = (wv << 4) + (lane & 15);
        const half8 gA0 = *(const half8*)(gb + arow * 64 + ((lane >> 4) << 3));
        const half8 gA1 = *(const half8*)(gb + arow * 64 + 32 + ((lane >> 4) << 3));
        float w22L[2][2] = {{0.f, 0.f}, {0.f, 0.f}};
        #pragma unroll
        for (int cap = 0; cap < 2; cap++)
            #pragma unroll
            for (int mt = 0; mt < 2; mt++) {
                f32x4 t = {0.f, 0.f, 0.f, 0.f};
                t = __builtin_amdgcn_mfma_f32_16x16x32_f16(gA0, af[cap][mt][0], t, 0, 0, 0);
                t = __builtin_amdgcn_mfma_f32_16x16x32_f16(gA1, af[cap][mt][1], t, 0, 0, 0);
                const int w = mt * 16 + (lane & 15);
                const int rp = (wv << 4) + ((lane >> 4) << 2);
                #pragma unroll
                for (int r = 0; r < 4; r++)
                    w22L[cap][mt] += t[r] * smt_read(&sSmT[cap][0], w, rp + r);
            }
        #pragma unroll
        for (int cap = 0; cap < 2; cap++)
            #pragma unroll
            for (int mt = 0; mt < 2; mt++) {
                w22L[cap][mt] += __shfl_xor(w22L[cap][mt], 16);
                w22L[cap][mt] += __shfl_xor(w22L[cap][mt], 32);
            }
        if (lane < 16) {
            #pragma unroll
            for (int cap = 0; cap < 2; cap++) {
                sW22[cap][wv][lane] = w22L[cap][0];
                sW22[cap][wv][16 + lane] = w22L[cap][1];
            }
        }
    }

    // w12 = sum_r sm[w,r] * capImg[w,r]
    {
        const int w = tid >> 3, rg = tid & 7;
        #pragma unroll
        for (int cap = 0; cap < 2; cap++) {
            float p = 0.f;
            if (MODE == 0) {
                #pragma unroll
                for (int k = 0; k < 8; k++) {
                    const int r = rg * 8 + k;
                    if (r < 36) {
                        float v = sAttn[r][cap * 32 + w]; v = (v >= 0.f) ? v : v * 10.f;
                        p += v * smt_read(&sSmT[cap][0], w, r);
                    }
                }
            } else {
                const size_t base = ((((size_t)((c0 + cap) * 32 + i)) << 5) + w) << 6;
                const half8 ci8 = *(const half8*)(capImg0 + base + rg * 8);
                #pragma unroll
                for (int k = 0; k < 8; k++) {
                    const int r = rg * 8 + k;
                    if (r < 36) p += (float)ci8[k] * smt_read(&sSmT[cap][0], w, r);
                }
            }
            p += __shfl_xor(p, 1); p += __shfl_xor(p, 2); p += __shfl_xor(p, 4);
            if (rg == 0) sW12f[cap][w] = p;
        }
    }
    __syncthreads();

    if (tid < 64) {
        const int cap = tid >> 5, w = tid & 31;
        const int lenc = cap ? len1 : len0;
        float part = 0.f;
        if (w < lenc) {
            const float a = sW12f[cap][w];
            const float b = sW22[cap][0][w] + sW22[cap][1][w] + sW22[cap][2][w] + sW22[cap][3][w];
            part = a / fmaxf(sqrtf(w11Buf[(c0 + cap) * 32 + w]) * sqrtf(b), EPS_);
        }
        part += __shfl_down(part, 16);
        part += __shfl_down(part, 8);
        part += __shfl_down(part, 4);
        part += __shfl_down(part, 2);
        part += __shfl_down(part, 1);
        if ((lane & 31) == 0) score[(c0 + cap) * 32 + i] += part / (float)lenc;
    }

    // ---- pre / qOut: imgW2T fragments shared by both captions; next-t prefetch ----
    if (MODE == 1) {
        f16 (*tiles)[4][32][66] = (f16(*)[4][32][66])sBig;   // [dbuf][cap*2+sub][w][j]
        const f16* w2base = imgW2T + (((size_t)i * 2048) << 6);
        half8 nb[2][2];
        {
            #pragma unroll
            for (int s = 0; s < 2; s++) {
                const int jA = (s * 4 + wv) * 16 + (lane & 15);    // subs 0,1
                const f16* bb = w2base + ((size_t)jA << 6);
                nb[s][0] = *(const half8*)(bb + ((lane >> 4) << 3));
                nb[s][1] = *(const half8*)(bb + 32 + ((lane >> 4) << 3));
            }
        }
        for (int t = 0; t < 16; t++) {
            half8 bf[2][2];
            #pragma unroll
            for (int s = 0; s < 2; s++) { bf[s][0] = nb[s][0]; bf[s][1] = nb[s][1]; }
            if (t < 15) {
                #pragma unroll
                for (int s = 0; s < 2; s++) {
                    const int sub = (t + 1) * 2 + s;
                    const int jA = (sub * 4 + wv) * 16 + (lane & 15);
                    const f16* bb = w2base + ((size_t)jA << 6);
                    nb[s][0] = *(const half8*)(bb + ((lane >> 4) << 3));
                    nb[s][1] = *(const half8*)(bb + 32 + ((lane >> 4) << 3));
                }
            }
            __builtin_amdgcn_s_setprio(1);
            #pragma unroll
            for (int s = 0; s < 2; s++)
                #pragma unroll
                for (int cap = 0; cap < 2; cap++)
                    #pragma unroll
                    for (int mt = 0; mt < 2; mt++) {
                        f32x4 acc = {0.f, 0.f, 0.f, 0.f};
                        acc = __builtin_amdgcn_mfma_f32_16x16x32_f16(bf[s][0], af[cap][mt][0], acc, 0, 0, 0);
                        acc = __builtin_amdgcn_mfma_f32_16x16x32_f16(bf[s][1], af[cap][mt][1], acc, 0, 0, 0);
                        const int w = mt * 16 + (lane & 15);
                        *(f16x4*)&tiles[t & 1][cap * 2 + s][w][wv * 16 + ((lane >> 4) << 2)] = to_h4(acc);
                    }
            __builtin_amdgcn_s_setprio(0);
            __syncthreads();
            const int w = tid >> 3, jg = tid & 7;
            #pragma unroll
            for (int s = 0; s < 2; s++) {
                const int sub = t * 2 + s;
                f16* dst = (sub < 16) ? preLin : preGate;
                const int joff = ((sub * 64) & 1023) + jg * 8;
                #pragma unroll
                for (int cap = 0; cap < 2; cap++) {
                    const int lenc = cap ? len1 : len0;
                    if (w < lenc) {
                        const half8 v = *(const half8*)&tiles[t & 1][cap * 2 + s][w][jg * 8];
                        *(half8*)(dst + (((size_t)((c0 + cap) * 32 + w) * 32 + i) << 10) + joff) = v;
                    }
                }
            }
        }
    } else if (MODE == 0) {
        f16 (*tiles)[4][32][66] = (f16(*)[4][32][66])sBig;  // [dbuf][cap*2+LG][w][j]
        const f16* w2base = imgW2T + (((size_t)i * 2048) << 6);
        half8 nL0, nL1, nG0, nG1;
        {
            const int jA = wv * 16 + (lane & 15);            // t = 0
            const f16* bbL = w2base + ((size_t)jA << 6);
            const f16* bbG = w2base + ((size_t)(1024 + jA) << 6);
            nL0 = *(const half8*)(bbL + ((lane >> 4) << 3));
            nL1 = *(const half8*)(bbL + 32 + ((lane >> 4) << 3));
            nG0 = *(const half8*)(bbG + ((lane >> 4) << 3));
            nG1 = *(const half8*)(bbG + 32 + ((lane >> 4) << 3));
        }
        for (int t = 0; t < 16; t++) {
            const half8 bL0 = nL0, bL1 = nL1, bG0 = nG0, bG1 = nG1;
            if (t < 15) {
                const int jA = ((t + 1) * 4 + wv) * 16 + (lane & 15);
                const f16* bbL = w2base + ((size_t)jA << 6);
                const f16* bbG = w2base + ((size_t)(1024 + jA) << 6);
                nL0 = *(const half8*)(bbL + ((lane >> 4) << 3));
                nL1 = *(const half8*)(bbL + 32 + ((lane >> 4) << 3));
                nG0 = *(const half8*)(bbG + ((lane >> 4) << 3));
                nG1 = *(const half8*)(bbG + 32 + ((lane >> 4) << 3));
            }
            __builtin_amdgcn_s_setprio(1);
            #pragma unroll
            for (int cap = 0; cap < 2; cap++)
                #pragma unroll
                for (int mt = 0; mt < 2; mt++) {
                    f32x4 aL = {0.f, 0.f, 0.f, 0.f}, aG = {0.f, 0.f, 0.f, 0.f};
                    aL = __builtin_amdgcn_mfma_f32_16x16x32_f16(bL0, af[cap][mt][0], aL, 0, 0, 0);
                    aL = __builtin_amdgcn_mfma_f32_16x16x32_f16(bL1, af[cap][mt][1], aL, 0, 0, 0);
                    aG = __builtin_amdgcn_mfma_f32_16x16x32_f16(bG0, af[cap][mt][0], aG, 0, 0, 0);
                    aG = __builtin_amdgcn_mfma_f32_16x16x32_f16(bG1, af[cap][mt][1], aG, 0, 0, 0);
                    const int w = mt * 16 + (lane & 15);
                    const int x = wv * 16 + ((lane >> 4) << 2);
                    *(f16x4*)&tiles[t & 1][cap * 2 + 0][w][x] = to_h4(aL);
                    *(f16x4*)&tiles[t & 1][cap * 2 + 1][w][x] = to_h4(aG);
                }
            __builtin_amdgcn_s_setprio(0);
            __syncthreads();
            const int w = tid >> 3, jg = tid & 7;
            const int j = t * 64 + jg * 8;
            #pragma unroll
            for (int cap = 0; cap < 2; cap++) {
                const int lenc = cap ? len1 : len0;
                if (w < lenc) {
                    const size_t cw = (size_t)((c0 + cap) * 32 + w);
                    const half8 l8 = *(const half8*)&tiles[t & 1][cap * 2 + 0][w][jg * 8];
                    const half8 g8 = *(const half8*)&tiles[t & 1][cap * 2 + 1][w][jg * 8];
                    const half8 c1L = *(const half8*)(capW1 + cw * 2048 + j);
                    const half8 c1G = *(const half8*)(capW1 + cw * 2048 + 1024 + j);
                    const half8 cp8 = *(const half8*)(capH + cw * 1024 + j);
                    half8 o;
                    #pragma unroll
                    for (int k = 0; k < 8; k++) {
                        const float h = tanhf((float)l8[k] + (float)c1L[k] + b_lin[j + k]);
                        const float g = 1.f / (1.f + __expf(-((float)g8[k] + (float)c1G[k] + b_gate[j + k])));
                        o[k] = (f16)((float)cp8[k] * g + h * (1.f - g));
                    }
                    *(half8*)(qOut + ((cw * 32 + i) << 10) + j) = o;
                }
            }
        }
    }
}

// q-half GEMM: m97 geometry. BM=128, BN=128 (64 j x {lin,gate}), BK=64,
// 256 thr / 4 waves (2m x 2n), acc[4][4], single-buffer LDS, 2-barrier K-step.
__global__ __launch_bounds__(256) void qgemm_kernel(
    const f16* __restrict__ Aptr,
    const f16* __restrict__ wlinH, const f16* __restrict__ wgateH,
    const f16* __restrict__ preLin, const f16* __restrict__ preGate,
    const float* __restrict__ b_lin, const float* __restrict__ b_gate,
    f16* __restrict__ outp,
    const int* __restrict__ lens,
    const int* __restrict__ tileMap, const int* __restrict__ activeCnt,
    const int mode)
{
    const int bid = blockIdx.x;
    int jt, cm;
    if (mode) {
        const int x = bid & 7;
        jt = (bid >> 3) & 15;
        const int s = bid >> 7;
        const int a = s * 8 + x;
        if (a >= activeCnt[0]) return;
        cm = tileMap[a];
    } else {
        jt = bid & 15; cm = bid >> 4;
    }
    int len = 32;
    if (mode) len = lens[cm >> 3];
    const int m0 = cm * 128;

    __shared__ f16 sA[128 * 64];
    __shared__ f16 sB[128 * 64];

    const int tid = threadIdx.x;
    const int lane = tid & 63;
    const int wv = tid >> 6;
    const int wm = wv >> 1;
    const int wn = wv & 1;

    f32x4 acc[4][4];
    #pragma unroll
    for (int a = 0; a < 4; a++)
        #pragma unroll
        for (int b = 0; b < 4; b++)
            acc[a][b] = (f32x4){0.f, 0.f, 0.f, 0.f};

    for (int ks = 0; ks < 16; ks++) {
        const int kk = ks * 64;
        #pragma unroll
        for (int p = 0; p < 4; p++) {
            const int idx = tid + p * 256;
            const int row = idx >> 3, ch = idx & 7;
            gload16(Aptr + (size_t)(m0 + row) * 1024 + kk + ((ch ^ (row & 7)) << 3),
                    (char*)sA + idx * 16);
        }
        #pragma unroll
        for (int p = 0; p < 4; p++) {
            const int idx = tid + p * 256;
            const int n = idx >> 3, ch = idx & 7;
            const int j = jt * 64 + (n & 63);
            const f16* wsrc = ((n < 64) ? wlinH : wgateH) + (size_t)j * 2048 + kk + ((ch ^ (n & 7)) << 3);
            gload16(wsrc, (char*)sB + idx * 16);
        }
        __syncthreads();
        #pragma unroll
        for (int ksub = 0; ksub < 2; ksub++) {
            const int k4 = (ksub << 2) | (lane >> 4);
            half8 afr[4], bfr[4];
            #pragma unroll
            for (int tm = 0; tm < 4; tm++) {
                const int row = wm * 64 + tm * 16 + (lane & 15);
                afr[tm] = *(const half8*)((const char*)sA + row * 128 + ((k4 ^ (row & 7)) << 4));
            }
            #pragma unroll
            for (int tn = 0; tn < 4; tn++) {
                const int n = wn * 64 + tn * 16 + (lane & 15);
                bfr[tn] = *(const half8*)((const char*)sB + n * 128 + ((k4 ^ (n & 7)) << 4));
            }
            #pragma unroll
            for (int tm = 0; tm < 4; tm++)
                #pragma unroll
                for (int tn = 0; tn < 4; tn++)
                    acc[tm][tn] = __builtin_amdgcn_mfma_f32_16x16x32_f16(afr[tm], bfr[tn], acc[tm][tn], 0, 0, 0);
        }
        __syncthreads();
    }

    // ---- LDS-staged epilogue: 2 passes of 64 rows, reuse sA/sB as C tiles
    f16 (*tl)[68] = (f16(*)[68])sA;
    f16 (*tg)[68] = (f16(*)[68])sB;
    const int j0 = (tid & 3) * 16;
    const int j = jt * 64 + j0;
    f32x4 blv[4], bgv[4];
    if (mode == 1) {
        #pragma unroll
        for (int q = 0; q < 4; q++) {
            blv[q] = *(const f32x4*)(b_lin + j + q * 4);
            bgv[q] = *(const f32x4*)(b_gate + j + q * 4);
        }
    }
    #pragma unroll
    for (int p = 0; p < 2; p++) {
        __syncthreads();
        if (wm == p) {
            #pragma unroll
            for (int tm = 0; tm < 4; tm++)
                #pragma unroll
                for (int tn = 0; tn < 4; tn++) {
                    const int n = wn * 64 + tn * 16 + (lane & 15);
                    #pragma unroll
                    for (int r = 0; r < 4; r++) {
                        const int ml = tm * 16 + ((lane >> 4) << 2) + r;
                        if (n < 64) tl[ml][n] = (f16)acc[tm][tn][r];
                        else        tg[ml][n - 64] = (f16)acc[tm][tn][r];
                    }
                }
        }
        __syncthreads();
        const int rl = tid >> 2;
        const int gm = m0 + p * 64 + rl;
        bool active = true;
        if (mode) active = (((gm >> 5) & 31) < len);
        if (active) {
            const half8 l0 = *(const half8*)&tl[rl][j0];
            const half8 l1 = *(const half8*)&tl[rl][j0 + 8];
            const half8 g0 = *(const half8*)&tg[rl][j0];
            const half8 g1 = *(const half8*)&tg[rl][j0 + 8];
            if (mode == 0) {
                *(half8*)(outp + (size_t)gm * 2048 + j) = l0;
                *(half8*)(outp + (size_t)gm * 2048 + j + 8) = l1;
                *(half8*)(outp + (size_t)gm * 2048 + 1024 + j) = g0;
                *(half8*)(outp + (size_t)gm * 2048 + 1024 + j + 8) = g1;
            } else {
                const size_t off = ((size_t)gm << 10) + j;
                const half8 pl0 = *(const half8*)(preLin + off);
                const half8 pl1 = *(const half8*)(preLin + off + 8);
                const half8 pg0 = *(const half8*)(preGate + off);
                const half8 pg1 = *(const half8*)(preGate + off + 8);
                const half8 qo0 = *(const half8*)(Aptr + off);
                const half8 qo1 = *(const half8*)(Aptr + off + 8);
                half8 o0, o1;
                #pragma unroll
                for (int k = 0; k < 8; k++) {
                    const float h = tanhf((float)l0[k] + (float)pl0[k] + blv[k >> 2][k & 3]);
                    const float g = 1.f / (1.f + __expf(-((float)g0[k] + (float)pg0[k] + bgv[k >> 2][k & 3])));
                    o0[k] = (f16)((float)qo0[k] * g + h * (1.f - g));
                }
                #pragma unroll
                for (int k = 0; k < 8; k++) {
                    const float h = tanhf((float)l1[k] + (float)pl1[k] + blv[2 + (k >> 2)][k & 3]);
                    const float g = 1.f / (1.f + __expf(-((float)g1[k] + (float)pg1[k] + bgv[2 + (k >> 2)][k & 3])));
                    o1[k] = (f16)((float)qo1[k] * g + h * (1.f - g));
                }
                *(half8*)(outp + off) = o0;
                *(half8*)(outp + off + 8) = o1;
            }
        }
    }
}

__global__ __launch_bounds__(64) void loss_kernel(const float* __restrict__ score,
                                                  float* __restrict__ out)
{
    __shared__ float s[32][33];
    __shared__ float diag[32];
    const int tid = threadIdx.x;
    for (int idx = tid; idx < 1024; idx += 64) s[idx >> 5][idx & 31] = score[idx];
    __syncthreads();
    if (tid < 32) diag[tid] = s[tid][tid];
    __syncthreads();
    float total = 0.f;
    if (tid < 32) {
        float m1 = 0.f, m2 = 0.f;
        for (int k = 0; k < 32; k++) {
            if (k != tid) {
                m1 = fmaxf(m1, fmaxf(0.f, MARGIN_ + s[tid][k] - diag[tid]));
                m2 = fmaxf(m2, fmaxf(0.f, MARGIN_ + s[k][tid] - diag[tid]));
            }
        }
        total = m1 + m2;
    }
    for (int off = 32; off > 0; off >>= 1) total += __shfl_down(total, off);
    if (tid == 0) out[0] = total;
}

extern "C" void kernel_launch(void* const* d_in, const int* in_sizes, int n_in,
                              void* d_out, int out_size, void* d_ws, size_t ws_size,
                              hipStream_t stream) {
    const float* img    = (const float*)d_in[0];
    const float* cap    = (const float*)d_in[1];
    const int*   lens   = (const int*)d_in[2];
    const float* w_lin  = (const float*)d_in[3];
    const float* b_lin  = (const float*)d_in[4];
    const float* w_gate = (const float*)d_in[5];
    const float* b_gate = (const float*)d_in[6];
    float* out = (float*)d_out;

    char* ws = (char*)d_ws;
    f16* qA      = (f16*)(ws);                       // 64 MB
    f16* preLin  = (f16*)(ws + 67108864);            // 64 MB (qB aliases)
    f16* preGate = (f16*)(ws + 134217728);           // 64 MB
    f16* capH    = (f16*)(ws + 201326592);           // 2 MB
    f16* wlinH   = (f16*)(ws + 203423744);           // 4 MB
    f16* wgateH  = (f16*)(ws + 207618048);           // 4 MB
    f16* imgH    = (f16*)(ws + 211812352);           // ~2.4 MB used
    f16* gramH   = (f16*)(ws + 214958080);           // 256 KB
    f16* capImg0 = (f16*)(ws + 216006656);           // 4 MB
    f16* imgW2T  = (f16*)(ws + 220200960);           // 8 MB
    f16* capW1   = (f16*)(ws + 228589568);           // 4 MB
    float* w11Buf = (float*)(ws + 232783872);        // 4 KB
    float* score  = (float*)(ws + 232787968);        // 4 KB
    int* tileMap  = (int*)(ws + 232792064);          // 1 KB
    int* activeCnt= (int*)(ws + 232793088);
    f16* qB = preLin;                                // alias

    hipMemsetAsync(score, 0, C_ * I_ * sizeof(float), stream);
    hipMemsetAsync(w11Buf, 0, C_ * W_ * sizeof(float), stream);
    convert_kernel<<<dim3(6272), dim3(256), 0, stream>>>(cap, w_lin, w_gate, img,
                                                         capH, wlinH, wgateH, imgH,
                                                         w11Buf, lens, tileMap, activeCnt);
    imgprep_kernel<<<dim3(544), dim3(256), 0, stream>>>(wlinH, wgateH, imgH, imgW2T, gramH);
    qgemm_kernel<<<dim3(128), dim3(256), 0, stream>>>(capH, wlinH, wgateH, (const f16*)0, (const f16*)0,
                                                      b_lin, b_gate, capW1, lens, tileMap, activeCnt, 0);
    // iter 0
    attn_kernel<0><<<dim3(512), dim3(256), 0, stream>>>(imgH, gramH, imgW2T, capH, (const f16*)0,
                                                        capW1, capImg0, b_lin, b_gate, w11Buf, lens,
                                                        preLin, preGate, qA, score);
    // iter 1
    attn_kernel<1><<<dim3(512), dim3(256), 0, stream>>>(imgH, gramH, imgW2T, capH, qA,
                                                        capW1, capImg0, b_lin, b_gate, w11Buf, lens,
                                                        preLin, preGate, (f16*)0, score);
    qgemm_kernel<<<dim3(2432), dim3(256), 0, stream>>>(qA, wlinH, wgateH, preLin, preGate,
                                                       b_lin, b_gate, qB, lens, tileMap, activeCnt, 1);
    // iter 2
    attn_kernel<2><<<dim3(512), dim3(256), 0, stream>>>(imgH, gramH, imgW2T, capH, qB,
                                                        capW1, capImg0, b_lin, b_gate, w11Buf, lens,
                                                        preLin, preGate, (f16*)0, score);

    loss_kernel<<<dim3(1), dim3(64), 0, stream>>>(score, out);
}

// Round 22
// 390.173 us; speedup vs baseline: 1.0802x; 1.0105x over previous
//
#include <hip/hip_runtime.h>
#include <hip/hip_fp16.h>

#define C_ 32
#define I_ 32
#define W_ 32
#define R_ 36
#define D_ 1024
#define EPS_ 1e-8f
#define LAMBDA_ 9.0f
#define MARGIN_ 0.2f

typedef _Float16 f16;
typedef f16 half8 __attribute__((ext_vector_type(8)));
typedef f16 f16x4 __attribute__((ext_vector_type(4)));
typedef float f32x4 __attribute__((ext_vector_type(4)));

__device__ __forceinline__ void gload16(const void* g, void* l) {
    __builtin_amdgcn_global_load_lds((const __attribute__((address_space(1))) void*)g,
                                     (__attribute__((address_space(3))) void*)l, 16, 0, 0);
}

__device__ __forceinline__ f16x4 to_h4(f32x4 v) {
    f16x4 o; o[0] = (f16)v[0]; o[1] = (f16)v[1]; o[2] = (f16)v[2]; o[3] = (f16)v[3];
    return o;
}

// fp32 -> fp16 of cap, w_lin, w_gate, img. Cap segment also accumulates
// w11Buf[row] = sum_d cap^2 via per-wave reduce + atomic (4/row).
// Block 0 thread 0 builds the active-tile map.
__global__ __launch_bounds__(256) void convert_kernel(
    const float* __restrict__ cap, const float* __restrict__ wl, const float* __restrict__ wg,
    const float* __restrict__ img,
    f16* __restrict__ capH, f16* __restrict__ wlH, f16* __restrict__ wgH, f16* __restrict__ imgH,
    float* __restrict__ w11Buf,
    const int* __restrict__ lens, int* __restrict__ tileMap, int* __restrict__ activeCnt)
{
    const int t = blockIdx.x * 256 + threadIdx.x;   // 1605632 total
    if (blockIdx.x == 0 && threadIdx.x == 0) {
        int n = 0;
        for (int cm = 0; cm < 256; cm++) {
            const int len = lens[cm >> 3];
            if ((cm & 7) * 4 < len) tileMap[n++] = cm;
        }
        activeCnt[0] = n;
    }
    const float* src; f16* dst; int idx;
    bool isCap = false;
    if (t < 262144)        { src = cap; dst = capH; idx = t; isCap = true; }
    else if (t < 786432)   { src = wl;  dst = wlH;  idx = t - 262144; }
    else if (t < 1310720)  { src = wg;  dst = wgH;  idx = t - 786432; }
    else                   { src = img; dst = imgH; idx = t - 1310720; }
    float4 v = ((const float4*)src)[idx];
    f16x4 o; o[0] = (f16)v.x; o[1] = (f16)v.y; o[2] = (f16)v.z; o[3] = (f16)v.w;
    *(f16x4*)(dst + (size_t)idx * 4) = o;
    if (isCap) {
        float s = v.x * v.x + v.y * v.y + v.z * v.z + v.w * v.w;
        #pragma unroll
        for (int m = 32; m > 0; m >>= 1) s += __shfl_xor(s, m);
        if ((threadIdx.x & 63) == 0) atomicAdd(&w11Buf[t >> 8], s);
    }
}

// Merged prep: bid<512 -> imgW2T tile (jt=bid&15, i=bid>>4);
//              512<=bid<544 -> gram (i=bid-512);
//              bid>=544 -> capW1 = capH @ W1pair^T (jt=(bid-544)&15, cm=(bid-544)>>4)
__global__ __launch_bounds__(256) void imgprep_kernel(
    const f16* __restrict__ wlinH, const f16* __restrict__ wgateH,
    const f16* __restrict__ imgH, f16* __restrict__ imgW2T, f16* __restrict__ gramH,
    const f16* __restrict__ capH, f16* __restrict__ capW1)
{
    __shared__ __align__(16) char sMem[32768];
    const int tid = threadIdx.x, lane = tid & 63, wv = tid >> 6;

    if (blockIdx.x < 512) {
        // ---- imgW2T[i][j][r] = sum_d img[i][r][d] * Wpair2[j][d] ----
        const int jt = blockIdx.x & 15;
        const int i  = blockIdx.x >> 4;
        f16* sA = (f16*)sMem;               // 128 x 64 (16 KB)
        f16* sB = (f16*)(sMem + 16384);     // 64 x 64 (8 KB)
        const int wm = wv >> 1, wn = wv & 1;
        f32x4 acc[4][2];
        #pragma unroll
        for (int a = 0; a < 4; a++) { acc[a][0] = (f32x4){0,0,0,0}; acc[a][1] = (f32x4){0,0,0,0}; }

        for (int ks = 0; ks < 16; ks++) {
            const int kk = ks * 64;
            __syncthreads();
            #pragma unroll
            for (int p = 0; p < 4; p++) {
                const int u = tid + p * 256;
                const int row = u >> 3, ch = u & 7;
                const int jr = jt * 128 + row;
                const f16* src = ((jr < 1024) ? (wlinH + (size_t)jr * 2048)
                                              : (wgateH + (size_t)(jr - 1024) * 2048))
                                 + 1024 + kk + ((ch ^ (row & 7)) << 3);
                gload16(src, (char*)sA + u * 16);
            }
            #pragma unroll
            for (int p = 0; p < 2; p++) {
                const int u = tid + p * 256;
                const int row = u >> 3, ch = u & 7;
                const f16* src = imgH + (size_t)(i * 36 + row) * 1024 + kk + ((ch ^ (row & 7)) << 3);
                gload16(src, (char*)sB + u * 16);
            }
            __syncthreads();
            #pragma unroll
            for (int ksub = 0; ksub < 2; ksub++) {
                const int kch = (ksub << 2) | (lane >> 4);
                half8 af[4], bf[2];
                #pragma unroll
                for (int tm = 0; tm < 4; tm++) {
                    const int row = wm * 64 + tm * 16 + (lane & 15);
                    af[tm] = *(const half8*)((const char*)sA + row * 128 + ((kch ^ (row & 7)) << 4));
                }
                #pragma unroll
                for (int tn = 0; tn < 2; tn++) {
                    const int row = wn * 32 + tn * 16 + (lane & 15);
                    bf[tn] = *(const half8*)((const char*)sB + row * 128 + ((kch ^ (row & 7)) << 4));
                }
                #pragma unroll
                for (int tm = 0; tm < 4; tm++)
                    #pragma unroll
                    for (int tn = 0; tn < 2; tn++)
                        acc[tm][tn] = __builtin_amdgcn_mfma_f32_16x16x32_f16(af[tm], bf[tn], acc[tm][tn], 0, 0, 0);
            }
        }
        #pragma unroll
        for (int tm = 0; tm < 4; tm++)
            #pragma unroll
            for (int tn = 0; tn < 2; tn++)
                #pragma unroll
                for (int r = 0; r < 4; r++) {
                    const int j = jt * 128 + wm * 64 + tm * 16 + (lane >> 4) * 4 + r;
                    const int rc = wn * 32 + tn * 16 + (lane & 15);
                    imgW2T[((size_t)i * 2048 + j) * 64 + rc] = (rc < 36) ? (f16)acc[tm][tn][r] : (f16)0.f;
                }
    } else if (blockIdx.x < 544) {
        // ---- gramH[i][m][n] = sum_d img[i][m][d] img[i][n][d] ----
        const int i = blockIdx.x - 512;
        f16 (*sG)[6144] = (f16(*)[6144])sMem;   // 2 x 48x128

        auto stage = [&](int b, int k0) {
            for (int g = wv; g < 12; g += 4) {
                const int row = g * 4 + (lane >> 4);
                gload16(imgH + (size_t)(i * 36 + row) * 1024 + k0 + (((lane & 15) ^ (row & 7)) << 3),
                        &sG[b][g * 512]);
            }
        };

        f32x4 acc[4];
        #pragma unroll
        for (int a = 0; a < 4; a++) acc[a] = (f32x4){0.f, 0.f, 0.f, 0.f};

        stage(0, 0);
        __syncthreads();
        int cur = 0;
        for (int kc = 0; kc < 8; kc++) {
            if (kc < 7) stage(cur ^ 1, (kc + 1) * 128);
            #pragma unroll
            for (int ks = 0; ks < 4; ks++) {
                const int arow = wv * 16 + (lane & 15);
                const half8 am = *(const half8*)&sG[cur][arow * 128 + ((((ks << 2) | (lane >> 4)) ^ (arow & 7)) << 3)];
                #pragma unroll
                for (int nt = 0; nt < 4; nt++) {
                    const int brow = nt * 16 + (lane & 15);
                    const half8 bn = *(const half8*)&sG[cur][brow * 128 + ((((ks << 2) | (lane >> 4)) ^ (brow & 7)) << 3)];
                    acc[nt] = __builtin_amdgcn_mfma_f32_16x16x32_f16(am, bn, acc[nt], 0, 0, 0);
                }
            }
            __syncthreads();
            cur ^= 1;
        }
        #pragma unroll
        for (int nt = 0; nt < 4; nt++)
            #pragma unroll
            for (int r = 0; r < 4; r++) {
                const int m = wv * 16 + ((lane >> 4) << 2) + r;
                const int n = nt * 16 + (lane & 15);
                gramH[(size_t)i * 4096 + m * 64 + n] = (m < 36 && n < 36) ? (f16)acc[nt][r] : (f16)0.f;
            }
    } else {
        // ---- capW1[m][...] = capH @ W1pair^T (m97 geometry, mode-0 epilogue) ----
        const int b2 = blockIdx.x - 544;    // 0..127
        const int jt = b2 & 15;
        const int cm = b2 >> 4;             // 0..7
        const int m0 = cm * 128;
        f16* sA = (f16*)sMem;               // 128 x 64 (16 KB)
        f16* sB = (f16*)(sMem + 16384);     // 128 x 64 (16 KB)
        const int wm = wv >> 1;
        const int wn = wv & 1;

        f32x4 acc[4][4];
        #pragma unroll
        for (int a = 0; a < 4; a++)
            #pragma unroll
            for (int b = 0; b < 4; b++)
                acc[a][b] = (f32x4){0.f, 0.f, 0.f, 0.f};

        for (int ks = 0; ks < 16; ks++) {
            const int kk = ks * 64;
            __syncthreads();
            #pragma unroll
            for (int p = 0; p < 4; p++) {
                const int idx = tid + p * 256;
                const int row = idx >> 3, ch = idx & 7;
                gload16(capH + (size_t)(m0 + row) * 1024 + kk + ((ch ^ (row & 7)) << 3),
                        (char*)sA + idx * 16);
            }
            #pragma unroll
            for (int p = 0; p < 4; p++) {
                const int idx = tid + p * 256;
                const int n = idx >> 3, ch = idx & 7;
                const int j = jt * 64 + (n & 63);
                const f16* wsrc = ((n < 64) ? wlinH : wgateH) + (size_t)j * 2048 + kk + ((ch ^ (n & 7)) << 3);
                gload16(wsrc, (char*)sB + idx * 16);
            }
            __syncthreads();
            #pragma unroll
            for (int ksub = 0; ksub < 2; ksub++) {
                const int k4 = (ksub << 2) | (lane >> 4);
                half8 afr[4], bfr[4];
                #pragma unroll
                for (int tm = 0; tm < 4; tm++) {
                    const int row = wm * 64 + tm * 16 + (lane & 15);
                    afr[tm] = *(const half8*)((const char*)sA + row * 128 + ((k4 ^ (row & 7)) << 4));
                }
                #pragma unroll
                for (int tn = 0; tn < 4; tn++) {
                    const int n = wn * 64 + tn * 16 + (lane & 15);
                    bfr[tn] = *(const half8*)((const char*)sB + n * 128 + ((k4 ^ (n & 7)) << 4));
                }
                #pragma unroll
                for (int tm = 0; tm < 4; tm++)
                    #pragma unroll
                    for (int tn = 0; tn < 4; tn++)
                        acc[tm][tn] = __builtin_amdgcn_mfma_f32_16x16x32_f16(afr[tm], bfr[tn], acc[tm][tn], 0, 0, 0);
            }
        }

        // LDS-staged epilogue (raw capW1 store), 2 passes of 64 rows
        f16 (*tl)[68] = (f16(*)[68])sA;
        f16 (*tg)[68] = (f16(*)[68])sB;
        const int j0 = (tid & 3) * 16;
        const int j = jt * 64 + j0;
        #pragma unroll
        for (int p = 0; p < 2; p++) {
            __syncthreads();
            if (wm == p) {
                #pragma unroll
                for (int tm = 0; tm < 4; tm++)
                    #pragma unroll
                    for (int tn = 0; tn < 4; tn++) {
                        const int n = wn * 64 + tn * 16 + (lane & 15);
                        #pragma unroll
                        for (int r = 0; r < 4; r++) {
                            const int ml = tm * 16 + ((lane >> 4) << 2) + r;
                            if (n < 64) tl[ml][n] = (f16)acc[tm][tn][r];
                            else        tg[ml][n - 64] = (f16)acc[tm][tn][r];
                        }
                    }
            }
            __syncthreads();
            const int rl = tid >> 2;
            const int gm = m0 + p * 64 + rl;
            const half8 l0 = *(const half8*)&tl[rl][j0];
            const half8 l1 = *(const half8*)&tl[rl][j0 + 8];
            const half8 g0 = *(const half8*)&tg[rl][j0];
            const half8 g1 = *(const half8*)&tg[rl][j0 + 8];
            *(half8*)(capW1 + (size_t)gm * 2048 + j) = l0;
            *(half8*)(capW1 + (size_t)gm * 2048 + j + 8) = l1;
            *(half8*)(capW1 + (size_t)gm * 2048 + 1024 + j) = g0;
            *(half8*)(capW1 + (size_t)gm * 2048 + 1024 + j + 8) = g1;
        }
    }
}

__device__ __forceinline__ float smt_read(const f16* sSmT, int w, int r) {
    return (float)sSmT[w * 64 + ((((r >> 3) ^ (w & 7)) << 3) | (r & 7))];
}

// One WG per (c-pair, i), 4 waves, 3 blocks/CU. Single-buffer phase A.
template<int MODE>
__global__ __launch_bounds__(256, 3) void attn_kernel(
    const f16* __restrict__ imgH,
    const f16* __restrict__ gramH,      // (I,64,64)
    const f16* __restrict__ imgW2T,     // (I,2048,64)
    const f16* __restrict__ capH,
    const f16* __restrict__ qcur,       // (C,W,I,D)
    const f16* __restrict__ capW1,      // (C*W,2048)
    f16* __restrict__ capImg0,          // (C,I,W,64)
    const float* __restrict__ b_lin, const float* __restrict__ b_gate,
    const float* __restrict__ w11Buf,
    const int* __restrict__ lens,
    f16* __restrict__ preLin, f16* __restrict__ preGate,
    f16* __restrict__ qOut,
    float* __restrict__ score)
{
    constexpr int SBIG = (MODE == 2) ? 28672 : 33792;
    __shared__ __align__(16) char sBig[SBIG];
    __shared__ f16 sSmT[2][2048];
    __shared__ float sAttn[36][66];     // cols 0..31 cap0, 32..63 cap1
    __shared__ float sNrm[2][36];
    __shared__ float sW22[2][4][32];
    __shared__ float sW12f[2][32];

    const int bid = blockIdx.x;         // 0..511
    const int cp = bid >> 5;            // caption pair
    const int i  = ((bid & 7) << 2) | ((bid >> 3) & 3);   // XCD: same-i colocate
    const int c0 = cp * 2;
    const int len0 = lens[c0], len1 = lens[c0 + 1];
    const int tid = threadIdx.x;
    const int lane = tid & 63;
    const int wv = tid >> 6;
    const int i36 = i * 36;

    f16* sPA = (f16*)sBig;

    f32x4 accA[3] = {{0,0,0,0},{0,0,0,0},{0,0,0,0}};
    const int lenW = (wv >> 1) ? len1 : len0;
    const bool skipW = (MODE != 0) && ((wv & 1) == 1) && (lenW <= 16);

    auto stageA = [&](int k0) {
        for (int g = wv; g < 28; g += 4) {
            if (g < 12) {
                const int row = g * 4 + (lane >> 4);
                gload16(imgH + (size_t)(i36 + row) * 1024 + k0 + (((lane & 15) ^ (row & 7)) << 3),
                        &sPA[g * 512]);
            } else {
                const int gq = g - 12;
                const int w = gq * 4 + (lane >> 4);          // 0..63 (2 captions)
                const int lenw = (w >> 5) ? len1 : len0;
                const f16* src = (MODE == 0)
                    ? (capH + (size_t)(c0 * 32 + w) * 1024)
                    : (qcur + (((size_t)(c0 * 32 + w)) * 32 + i) * 1024);
                src += k0 + (((lane & 15) ^ (w & 7)) << 3);
                if (MODE == 0 || (w & 31) < lenw)
                    gload16(src, &sPA[6144 + gq * 512]);
            }
        }
    };

    for (int kc = 0; kc < 8; kc++) {
        stageA(kc * 128);
        __syncthreads();
        if (!skipW) {
            __builtin_amdgcn_s_setprio(1);
            #pragma unroll
            for (int ks = 0; ks < 4; ks++) {
                const int kch = (ks << 2) | (lane >> 4);
                const int brow = wv * 16 + (lane & 15);
                const half8 bf = *(const half8*)&sPA[6144 + brow * 128 + ((kch ^ (brow & 7)) << 3)];
                #pragma unroll
                for (int mt = 0; mt < 3; mt++) {
                    const int arow = mt * 16 + (lane & 15);
                    const half8 af = *(const half8*)&sPA[arow * 128 + ((kch ^ (arow & 7)) << 3)];
                    accA[mt] = __builtin_amdgcn_mfma_f32_16x16x32_f16(af, bf, accA[mt], 0, 0, 0);
                }
            }
            __builtin_amdgcn_s_setprio(0);
        }
        __syncthreads();
    }

    if (!skipW) {
        #pragma unroll
        for (int mt = 0; mt < 3; mt++) {
            #pragma unroll
            for (int r = 0; r < 4; r++) {
                const int rr = mt * 16 + (lane >> 4) * 4 + r;
                if (rr < 36) {
                    float v = accA[mt][r];
                    sAttn[rr][wv * 16 + (lane & 15)] = (v >= 0.f) ? v : 0.1f * v;
                }
            }
        }
    }
    __syncthreads();

    if (tid < 72) {
        const int cap = tid / 36;
        const int r = tid - cap * 36;
        const int lenc = cap ? len1 : len0;
        float s = 0.f;
        for (int w = 0; w < lenc; w++) { float v = sAttn[r][cap * 32 + w]; s += v * v; }
        sNrm[cap][r] = LAMBDA_ / (sqrtf(s) + EPS_);
    }
    __syncthreads();

    if (tid < 64) {
        const int cap = tid >> 5, w = tid & 31;
        const int lenc = cap ? len1 : len0;
        f16* smt = &sSmT[cap][0];
        if (w < lenc) {
            float m = -1e30f;
            #pragma unroll
            for (int r = 0; r < 36; r++) m = fmaxf(m, sAttn[r][cap * 32 + w] * sNrm[cap][r]);
            float sum = 0.f;
            #pragma unroll
            for (int r = 0; r < 36; r++) sum += __expf(sAttn[r][cap * 32 + w] * sNrm[cap][r] - m);
            const float inv = 1.0f / sum;
            #pragma unroll
            for (int r = 0; r < 64; r++) {
                const int off = w * 64 + ((((r >> 3) ^ (w & 7)) << 3) | (r & 7));
                smt[off] = (r < 36) ? (f16)(__expf(sAttn[r][cap * 32 + w] * sNrm[cap][r] - m) * inv) : (f16)0.f;
            }
        } else {
            #pragma unroll
            for (int r = 0; r < 64; r++) smt[w * 64 + r] = (f16)0.f;
        }
    }
    __syncthreads();

    if (MODE == 0) {
        const int w = tid >> 3, rg = tid & 7;
        #pragma unroll
        for (int cap = 0; cap < 2; cap++) {
            half8 o;
            #pragma unroll
            for (int k = 0; k < 8; k++) {
                const int r = rg * 8 + k;
                float v = 0.f;
                if (r < 36) { v = sAttn[r][cap * 32 + w]; v = (v >= 0.f) ? v : v * 10.f; }
                o[k] = (f16)v;
            }
            const size_t base = ((((size_t)((c0 + cap) * 32 + i)) << 5) + w) << 6;
            *(half8*)(capImg0 + base + rg * 8) = o;
        }
    }

    half8 af[2][2][2];
    #pragma unroll
    for (int cap = 0; cap < 2; cap++)
        #pragma unroll
        for (int mt = 0; mt < 2; mt++)
            #pragma unroll
            for (int ks = 0; ks < 2; ks++) {
                const int row = mt * 16 + (lane & 15);
                af[cap][mt][ks] = *(const half8*)&sSmT[cap][row * 64 + ((((ks << 2) | (lane >> 4)) ^ (row & 7)) << 3)];
            }

    // w22 = sm^T G sm (gram rows shared by both captions)
    {
        const f16* gb = gramH + ((size_t)i << 12);
        const int arow = (wv << 4) + (lane & 15);
        const half8 gA0 = *(const half8*)(gb + arow * 64 + ((lane >> 4) << 3));
        const half8 gA1 = *(const half8*)(gb + arow * 64 + 32 + ((lane >> 4) << 3));
        float w22L[2][2] = {{0.f, 0.f}, {0.f, 0.f}};
        #pragma unroll
        for (int cap = 0; cap < 2; cap++)
            #pragma unroll
            for (int mt = 0; mt < 2; mt++) {
                f32x4 t = {0.f, 0.f, 0.f, 0.f};
                t = __builtin_amdgcn_mfma_f32_16x16x32_f16(gA0, af[cap][mt][0], t, 0, 0, 0);
                t = __builtin_amdgcn_mfma_f32_16x16x32_f16(gA1, af[cap][mt][1], t, 0, 0, 0);
                const int w = mt * 16 + (lane & 15);
                const int rp = (wv << 4) + ((lane >> 4) << 2);
                #pragma unroll
                for (int r = 0; r < 4; r++)
                    w22L[cap][mt] += t[r] * smt_read(&sSmT[cap][0], w, rp + r);
            }
        #pragma unroll
        for (int cap = 0; cap < 2; cap++)
            #pragma unroll
            for (int mt = 0; mt < 2; mt++) {
                w22L[cap][mt] += __shfl_xor(w22L[cap][mt], 16);
                w22L[cap][mt] += __shfl_xor(w22L[cap][mt], 32);
            }
        if (lane < 16) {
            #pragma unroll
            for (int cap = 0; cap < 2; cap++) {
                sW22[cap][wv][lane] = w22L[cap][0];
                sW22[cap][wv][16 + lane] = w22L[cap][1];
            }
        }
    }

    // w12 = sum_r sm[w,r] * capImg[w,r]
    {
        const int w = tid >> 3, rg = tid & 7;
        #pragma unroll
        for (int cap = 0; cap < 2; cap++) {
            float p = 0.f;
            if (MODE == 0) {
                #pragma unroll
                for (int k = 0; k < 8; k++) {
                    const int r = rg * 8 + k;
                    if (r < 36) {
                        float v = sAttn[r][cap * 32 + w]; v = (v >= 0.f) ? v : v * 10.f;
                        p += v * smt_read(&sSmT[cap][0], w, r);
                    }
                }
            } else {
                const size_t base = ((((size_t)((c0 + cap) * 32 + i)) << 5) + w) << 6;
                const half8 ci8 = *(const half8*)(capImg0 + base + rg * 8);
                #pragma unroll
                for (int k = 0; k < 8; k++) {
                    const int r = rg * 8 + k;
                    if (r < 36) p += (float)ci8[k] * smt_read(&sSmT[cap][0], w, r);
                }
            }
            p += __shfl_xor(p, 1); p += __shfl_xor(p, 2); p += __shfl_xor(p, 4);
            if (rg == 0) sW12f[cap][w] = p;
        }
    }
    __syncthreads();

    if (tid < 64) {
        const int cap = tid >> 5, w = tid & 31;
        const int lenc = cap ? len1 : len0;
        float part = 0.f;
        if (w < lenc) {
            const float a = sW12f[cap][w];
            const float b = sW22[cap][0][w] + sW22[cap][1][w] + sW22[cap][2][w] + sW22[cap][3][w];
            part = a / fmaxf(sqrtf(w11Buf[(c0 + cap) * 32 + w]) * sqrtf(b), EPS_);
        }
        part += __shfl_down(part, 16);
        part += __shfl_down(part, 8);
        part += __shfl_down(part, 4);
        part += __shfl_down(part, 2);
        part += __shfl_down(part, 1);
        if ((lane & 31) == 0) score[(c0 + cap) * 32 + i] += part / (float)lenc;
    }

    // ---- pre / qOut: imgW2T fragments shared by both captions; next-t prefetch ----
    if (MODE == 1) {
        f16 (*tiles)[4][32][66] = (f16(*)[4][32][66])sBig;   // [dbuf][cap*2+sub][w][j]
        const f16* w2base = imgW2T + (((size_t)i * 2048) << 6);
        half8 nb[2][2];
        {
            #pragma unroll
            for (int s = 0; s < 2; s++) {
                const int jA = (s * 4 + wv) * 16 + (lane & 15);    // subs 0,1
                const f16* bb = w2base + ((size_t)jA << 6);
                nb[s][0] = *(const half8*)(bb + ((lane >> 4) << 3));
                nb[s][1] = *(const half8*)(bb + 32 + ((lane >> 4) << 3));
            }
        }
        for (int t = 0; t < 16; t++) {
            half8 bf[2][2];
            #pragma unroll
            for (int s = 0; s < 2; s++) { bf[s][0] = nb[s][0]; bf[s][1] = nb[s][1]; }
            if (t < 15) {
                #pragma unroll
                for (int s = 0; s < 2; s++) {
                    const int sub = (t + 1) * 2 + s;
                    const int jA = (sub * 4 + wv) * 16 + (lane & 15);
                    const f16* bb = w2base + ((size_t)jA << 6);
                    nb[s][0] = *(const half8*)(bb + ((lane >> 4) << 3));
                    nb[s][1] = *(const half8*)(bb + 32 + ((lane >> 4) << 3));
                }
            }
            __builtin_amdgcn_s_setprio(1);
            #pragma unroll
            for (int s = 0; s < 2; s++)
                #pragma unroll
                for (int cap = 0; cap < 2; cap++)
                    #pragma unroll
                    for (int mt = 0; mt < 2; mt++) {
                        f32x4 acc = {0.f, 0.f, 0.f, 0.f};
                        acc = __builtin_amdgcn_mfma_f32_16x16x32_f16(bf[s][0], af[cap][mt][0], acc, 0, 0, 0);
                        acc = __builtin_amdgcn_mfma_f32_16x16x32_f16(bf[s][1], af[cap][mt][1], acc, 0, 0, 0);
                        const int w = mt * 16 + (lane & 15);
                        *(f16x4*)&tiles[t & 1][cap * 2 + s][w][wv * 16 + ((lane >> 4) << 2)] = to_h4(acc);
                    }
            __builtin_amdgcn_s_setprio(0);
            __syncthreads();
            const int w = tid >> 3, jg = tid & 7;
            #pragma unroll
            for (int s = 0; s < 2; s++) {
                const int sub = t * 2 + s;
                f16* dst = (sub < 16) ? preLin : preGate;
                const int joff = ((sub * 64) & 1023) + jg * 8;
                #pragma unroll
                for (int cap = 0; cap < 2; cap++) {
                    const int lenc = cap ? len1 : len0;
                    if (w < lenc) {
                        const half8 v = *(const half8*)&tiles[t & 1][cap * 2 + s][w][jg * 8];
                        *(half8*)(dst + (((size_t)((c0 + cap) * 32 + w) * 32 + i) << 10) + joff) = v;
                    }
                }
            }
        }
    } else if (MODE == 0) {
        f16 (*tiles)[4][32][66] = (f16(*)[4][32][66])sBig;  // [dbuf][cap*2+LG][w][j]
        const f16* w2base = imgW2T + (((size_t)i * 2048) << 6);
        half8 nL0, nL1, nG0, nG1;
        {
            const int jA = wv * 16 + (lane & 15);            // t = 0
            const f16* bbL = w2base + ((size_t)jA << 6);
            const f16* bbG = w2base + ((size_t)(1024 + jA) << 6);
            nL0 = *(const half8*)(bbL + ((lane >> 4) << 3));
            nL1 = *(const half8*)(bbL + 32 + ((lane >> 4) << 3));
            nG0 = *(const half8*)(bbG + ((lane >> 4) << 3));
            nG1 = *(const half8*)(bbG + 32 + ((lane >> 4) << 3));
        }
        for (int t = 0; t < 16; t++) {
            const half8 bL0 = nL0, bL1 = nL1, bG0 = nG0, bG1 = nG1;
            if (t < 15) {
                const int jA = ((t + 1) * 4 + wv) * 16 + (lane & 15);
                const f16* bbL = w2base + ((size_t)jA << 6);
                const f16* bbG = w2base + ((size_t)(1024 + jA) << 6);
                nL0 = *(const half8*)(bbL + ((lane >> 4) << 3));
                nL1 = *(const half8*)(bbL + 32 + ((lane >> 4) << 3));
                nG0 = *(const half8*)(bbG + ((lane >> 4) << 3));
                nG1 = *(const half8*)(bbG + 32 + ((lane >> 4) << 3));
            }
            __builtin_amdgcn_s_setprio(1);
            #pragma unroll
            for (int cap = 0; cap < 2; cap++)
                #pragma unroll
                for (int mt = 0; mt < 2; mt++) {
                    f32x4 aL = {0.f, 0.f, 0.f, 0.f}, aG = {0.f, 0.f, 0.f, 0.f};
                    aL = __builtin_amdgcn_mfma_f32_16x16x32_f16(bL0, af[cap][mt][0], aL, 0, 0, 0);
                    aL = __builtin_amdgcn_mfma_f32_16x16x32_f16(bL1, af[cap][mt][1], aL, 0, 0, 0);
                    aG = __builtin_amdgcn_mfma_f32_16x16x32_f16(bG0, af[cap][mt][0], aG, 0, 0, 0);
                    aG = __builtin_amdgcn_mfma_f32_16x16x32_f16(bG1, af[cap][mt][1], aG, 0, 0, 0);
                    const int w = mt * 16 + (lane & 15);
                    const int x = wv * 16 + ((lane >> 4) << 2);
                    *(f16x4*)&tiles[t & 1][cap * 2 + 0][w][x] = to_h4(aL);
                    *(f16x4*)&tiles[t & 1][cap * 2 + 1][w][x] = to_h4(aG);
                }
            __builtin_amdgcn_s_setprio(0);
            __syncthreads();
            const int w = tid >> 3, jg = tid & 7;
            const int j = t * 64 + jg * 8;
            #pragma unroll
            for (int cap = 0; cap < 2; cap++) {
                const int lenc = cap ? len1 : len0;
                if (w < lenc) {
                    const size_t cw = (size_t)((c0 + cap) * 32 + w);
                    const half8 l8 = *(const half8*)&tiles[t & 1][cap * 2 + 0][w][jg * 8];
                    const half8 g8 = *(const half8*)&tiles[t & 1][cap * 2 + 1][w][jg * 8];
                    const half8 c1L = *(const half8*)(capW1 + cw * 2048 + j);
                    const half8 c1G = *(const half8*)(capW1 + cw * 2048 + 1024 + j);
                    const half8 cp8 = *(const half8*)(capH + cw * 1024 + j);
                    half8 o;
                    #pragma unroll
                    for (int k = 0; k < 8; k++) {
                        const float h = tanhf((float)l8[k] + (float)c1L[k] + b_lin[j + k]);
                        const float g = 1.f / (1.f + __expf(-((float)g8[k] + (float)c1G[k] + b_gate[j + k])));
                        o[k] = (f16)((float)cp8[k] * g + h * (1.f - g));
                    }
                    *(half8*)(qOut + ((cw * 32 + i) << 10) + j) = o;
                }
            }
        }
    }
}

// q-half GEMM (mode-1 only now): m97 geometry. BM=128, BN=128, BK=64,
// 256 thr / 4 waves (2m x 2n), acc[4][4], single-buffer LDS, 2-barrier K-step.
__global__ __launch_bounds__(256) void qgemm_kernel(
    const f16* __restrict__ Aptr,
    const f16* __restrict__ wlinH, const f16* __restrict__ wgateH,
    const f16* __restrict__ preLin, const f16* __restrict__ preGate,
    const float* __restrict__ b_lin, const float* __restrict__ b_gate,
    f16* __restrict__ outp,
    const int* __restrict__ lens,
    const int* __restrict__ tileMap, const int* __restrict__ activeCnt)
{
    const int bid = blockIdx.x;
    const int x = bid & 7;
    const int jt = (bid >> 3) & 15;
    const int s = bid >> 7;
    const int a = s * 8 + x;
    if (a >= activeCnt[0]) return;
    const int cm = tileMap[a];
    const int len = lens[cm >> 3];
    const int m0 = cm * 128;

    __shared__ f16 sA[128 * 64];
    __shared__ f16 sB[128 * 64];

    const int tid = threadIdx.x;
    const int lane = tid & 63;
    const int wv = tid >> 6;
    const int wm = wv >> 1;
    const int wn = wv & 1;

    f32x4 acc[4][4];
    #pragma unroll
    for (int a2 = 0; a2 < 4; a2++)
        #pragma unroll
        for (int b = 0; b < 4; b++)
            acc[a2][b] = (f32x4){0.f, 0.f, 0.f, 0.f};

    for (int ks = 0; ks < 16; ks++) {
        const int kk = ks * 64;
        #pragma unroll
        for (int p = 0; p < 4; p++) {
            const int idx = tid + p * 256;
            const int row = idx >> 3, ch = idx & 7;
            gload16(Aptr + (size_t)(m0 + row) * 1024 + kk + ((ch ^ (row & 7)) << 3),
                    (char*)sA + idx * 16);
        }
        #pragma unroll
        for (int p = 0; p < 4; p++) {
            const int idx = tid + p * 256;
            const int n = idx >> 3, ch = idx & 7;
            const int j = jt * 64 + (n & 63);
            const f16* wsrc = ((n < 64) ? wlinH : wgateH) + (size_t)j * 2048 + kk + ((ch ^ (n & 7)) << 3);
            gload16(wsrc, (char*)sB + idx * 16);
        }
        __syncthreads();
        #pragma unroll
        for (int ksub = 0; ksub < 2; ksub++) {
            const int k4 = (ksub << 2) | (lane >> 4);
            half8 afr[4], bfr[4];
            #pragma unroll
            for (int tm = 0; tm < 4; tm++) {
                const int row = wm * 64 + tm * 16 + (lane & 15);
                afr[tm] = *(const half8*)((const char*)sA + row * 128 + ((k4 ^ (row & 7)) << 4));
            }
            #pragma unroll
            for (int tn = 0; tn < 4; tn++) {
                const int n = wn * 64 + tn * 16 + (lane & 15);
                bfr[tn] = *(const half8*)((const char*)sB + n * 128 + ((k4 ^ (n & 7)) << 4));
            }
            #pragma unroll
            for (int tm = 0; tm < 4; tm++)
                #pragma unroll
                for (int tn = 0; tn < 4; tn++)
                    acc[tm][tn] = __builtin_amdgcn_mfma_f32_16x16x32_f16(afr[tm], bfr[tn], acc[tm][tn], 0, 0, 0);
        }
        __syncthreads();
    }

    // ---- LDS-staged epilogue: 2 passes of 64 rows, reuse sA/sB as C tiles
    f16 (*tl)[68] = (f16(*)[68])sA;
    f16 (*tg)[68] = (f16(*)[68])sB;
    const int j0 = (tid & 3) * 16;
    const int j = jt * 64 + j0;
    f32x4 blv[4], bgv[4];
    #pragma unroll
    for (int q = 0; q < 4; q++) {
        blv[q] = *(const f32x4*)(b_lin + j + q * 4);
        bgv[q] = *(const f32x4*)(b_gate + j + q * 4);
    }
    #pragma unroll
    for (int p = 0; p < 2; p++) {
        __syncthreads();
        if (wm == p) {
            #pragma unroll
            for (int tm = 0; tm < 4; tm++)
                #pragma unroll
                for (int tn = 0; tn < 4; tn++) {
                    const int n = wn * 64 + tn * 16 + (lane & 15);
                    #pragma unroll
                    for (int r = 0; r < 4; r++) {
                        const int ml = tm * 16 + ((lane >> 4) << 2) + r;
                        if (n < 64) tl[ml][n] = (f16)acc[tm][tn][r];
                        else        tg[ml][n - 64] = (f16)acc[tm][tn][r];
                    }
                }
        }
        __syncthreads();
        const int rl = tid >> 2;
        const int gm = m0 + p * 64 + rl;
        const bool active = (((gm >> 5) & 31) < len);
        if (active) {
            const half8 l0 = *(const half8*)&tl[rl][j0];
            const half8 l1 = *(const half8*)&tl[rl][j0 + 8];
            const half8 g0 = *(const half8*)&tg[rl][j0];
            const half8 g1 = *(const half8*)&tg[rl][j0 + 8];
            const size_t off = ((size_t)gm << 10) + j;
            const half8 pl0 = *(const half8*)(preLin + off);
            const half8 pl1 = *(const half8*)(preLin + off + 8);
            const half8 pg0 = *(const half8*)(preGate + off);
            const half8 pg1 = *(const half8*)(preGate + off + 8);
            const half8 qo0 = *(const half8*)(Aptr + off);
            const half8 qo1 = *(const half8*)(Aptr + off + 8);
            half8 o0, o1;
            #pragma unroll
            for (int k = 0; k < 8; k++) {
                const float h = tanhf((float)l0[k] + (float)pl0[k] + blv[k >> 2][k & 3]);
                const float g = 1.f / (1.f + __expf(-((float)g0[k] + (float)pg0[k] + bgv[k >> 2][k & 3])));
                o0[k] = (f16)((float)qo0[k] * g + h * (1.f - g));
            }
            #pragma unroll
            for (int k = 0; k < 8; k++) {
                const float h = tanhf((float)l1[k] + (float)pl1[k] + blv[2 + (k >> 2)][k & 3]);
                const float g = 1.f / (1.f + __expf(-((float)g1[k] + (float)pg1[k] + bgv[2 + (k >> 2)][k & 3])));
                o1[k] = (f16)((float)qo1[k] * g + h * (1.f - g));
            }
            *(half8*)(outp + off) = o0;
            *(half8*)(outp + off + 8) = o1;
        }
    }
}

__global__ __launch_bounds__(64) void loss_kernel(const float* __restrict__ score,
                                                  float* __restrict__ out)
{
    __shared__ float s[32][33];
    __shared__ float diag[32];
    const int tid = threadIdx.x;
    for (int idx = tid; idx < 1024; idx += 64) s[idx >> 5][idx & 31] = score[idx];
    __syncthreads();
    if (tid < 32) diag[tid] = s[tid][tid];
    __syncthreads();
    float total = 0.f;
    if (tid < 32) {
        float m1 = 0.f, m2 = 0.f;
        for (int k = 0; k < 32; k++) {
            if (k != tid) {
                m1 = fmaxf(m1, fmaxf(0.f, MARGIN_ + s[tid][k] - diag[tid]));
                m2 = fmaxf(m2, fmaxf(0.f, MARGIN_ + s[k][tid] - diag[tid]));
            }
        }
        total = m1 + m2;
    }
    for (int off = 32; off > 0; off >>= 1) total += __shfl_down(total, off);
    if (tid == 0) out[0] = total;
}

extern "C" void kernel_launch(void* const* d_in, const int* in_sizes, int n_in,
                              void* d_out, int out_size, void* d_ws, size_t ws_size,
                              hipStream_t stream) {
    const float* img    = (const float*)d_in[0];
    const float* cap    = (const float*)d_in[1];
    const int*   lens   = (const int*)d_in[2];
    const float* w_lin  = (const float*)d_in[3];
    const float* b_lin  = (const float*)d_in[4];
    const float* w_gate = (const float*)d_in[5];
    const float* b_gate = (const float*)d_in[6];
    float* out = (float*)d_out;

    char* ws = (char*)d_ws;
    f16* qA      = (f16*)(ws);                       // 64 MB
    f16* preLin  = (f16*)(ws + 67108864);            // 64 MB (qB aliases)
    f16* preGate = (f16*)(ws + 134217728);           // 64 MB
    f16* capH    = (f16*)(ws + 201326592);           // 2 MB
    f16* wlinH   = (f16*)(ws + 203423744);           // 4 MB
    f16* wgateH  = (f16*)(ws + 207618048);           // 4 MB
    f16* imgH    = (f16*)(ws + 211812352);           // ~2.4 MB used
    f16* gramH   = (f16*)(ws + 214958080);           // 256 KB
    f16* capImg0 = (f16*)(ws + 216006656);           // 4 MB
    f16* imgW2T  = (f16*)(ws + 220200960);           // 8 MB
    f16* capW1   = (f16*)(ws + 228589568);           // 4 MB
    float* w11Buf = (float*)(ws + 232783872);        // 4 KB
    float* score  = (float*)(ws + 232787968);        // 4 KB
    int* tileMap  = (int*)(ws + 232792064);          // 1 KB
    int* activeCnt= (int*)(ws + 232793088);
    f16* qB = preLin;                                // alias

    hipMemsetAsync(score, 0, C_ * I_ * sizeof(float), stream);
    hipMemsetAsync(w11Buf, 0, C_ * W_ * sizeof(float), stream);
    convert_kernel<<<dim3(6272), dim3(256), 0, stream>>>(cap, w_lin, w_gate, img,
                                                         capH, wlinH, wgateH, imgH,
                                                         w11Buf, lens, tileMap, activeCnt);
    imgprep_kernel<<<dim3(672), dim3(256), 0, stream>>>(wlinH, wgateH, imgH, imgW2T, gramH,
                                                        capH, capW1);
    // iter 0
    attn_kernel<0><<<dim3(512), dim3(256), 0, stream>>>(imgH, gramH, imgW2T, capH, (const f16*)0,
                                                        capW1, capImg0, b_lin, b_gate, w11Buf, lens,
                                                        preLin, preGate, qA, score);
    // iter 1
    attn_kernel<1><<<dim3(512), dim3(256), 0, stream>>>(imgH, gramH, imgW2T, capH, qA,
                                                        capW1, capImg0, b_lin, b_gate, w11Buf, lens,
                                                        preLin, preGate, (f16*)0, score);
    qgemm_kernel<<<dim3(2432), dim3(256), 0, stream>>>(qA, wlinH, wgateH, preLin, preGate,
                                                       b_lin, b_gate, qB, lens, tileMap, activeCnt);
    // iter 2
    attn_kernel<2><<<dim3(512), dim3(256), 0, stream>>>(imgH, gramH, imgW2T, capH, qB,
                                                        capW1, capImg0, b_lin, b_gate, w11Buf, lens,
                                                        preLin, preGate, (f16*)0, score);

    loss_kernel<<<dim3(1), dim3(64), 0, stream>>>(score, out);
}